// Round 1
// baseline (588.439 us; speedup 1.0000x reference)
//
#include <hip/hip_runtime.h>
#include <hip/hip_bf16.h>

// Qwen3 attention block, bf16-MFMA pipeline.
// B=2 T=2048 HID=1536 H=12 HKV=2 D=128. All I/O fp32; internal compute bf16.

#define B_   2
#define T_   2048
#define HID_ 1536
#define H_   12
#define HKV_ 2
#define D_   128
#define GQ_  (H_ / HKV_)
#define SCALE_ 0.08838834764831845f  // 1/sqrt(128), folded into Q at cast time

typedef unsigned short u16;
typedef __attribute__((ext_vector_type(4))) float f32x4;
typedef __attribute__((ext_vector_type(8))) short bf16x8;
typedef __attribute__((ext_vector_type(4))) unsigned short u16x4;

__device__ __forceinline__ u16 f2b(float f) {
  union { __hip_bfloat16 h; u16 u; } cv;
  cv.h = __float2bfloat16(f);   // RNE
  return cv.u;
}

// stage 4 elements (fp32 -> bf16 convert, or bf16 passthrough) into LDS
__device__ __forceinline__ void ldcvt4(const float* p, u16* dst) {
  const float4 v = *reinterpret_cast<const float4*>(p);
  u16x4 o = { f2b(v.x), f2b(v.y), f2b(v.z), f2b(v.w) };
  *reinterpret_cast<u16x4*>(dst) = o;
}
__device__ __forceinline__ void ldcvt4(const u16* p, u16* dst) {
  *reinterpret_cast<u16x4*>(dst) = *reinterpret_cast<const u16x4*>(p);
}

// C[M][N] = A[M][K] * W[N][K]^T   (W row-major [N][K] == B^T form, contiguous-K frags)
// 128x128 tile, BK=32, 4 waves in 2x2, each wave 64x64 = 4x4 MFMA frags.
template <typename AT>
__global__ __launch_bounds__(256) void gemm_bt(const AT* __restrict__ A,
                                               const float* __restrict__ W,
                                               float* __restrict__ C,
                                               int M, int N, int K) {
  __shared__ u16 As[128][40];  // +8 pad: 80B rows -> 2-way LDS conflict (free), 16B aligned
  __shared__ u16 Ws[128][40];
  const int tid  = threadIdx.x;
  const int lane = tid & 63;
  const int wid  = tid >> 6;
  const int wr = wid >> 1, wc = wid & 1;
  const int l15 = lane & 15, kg = lane >> 4;
  const int rowBase = blockIdx.y * 128;
  const int colBase = blockIdx.x * 128;

  const f32x4 zero4 = {0.f, 0.f, 0.f, 0.f};
  f32x4 acc[4][4];
#pragma unroll
  for (int m = 0; m < 4; ++m)
#pragma unroll
    for (int n = 0; n < 4; ++n) acc[m][n] = zero4;

  for (int k0 = 0; k0 < K; k0 += 32) {
    // stage 128x32 of A and W: 1024 4-elem slots each, 256 threads x 4 iters
#pragma unroll
    for (int i = 0; i < 4; ++i) {
      const int s = tid + i * 256;
      const int r = s >> 3, c4 = (s & 7) << 2;
      ldcvt4(A + (size_t)(rowBase + r) * K + (k0 + c4), &As[r][c4]);
      ldcvt4(W + (size_t)(colBase + r) * K + (k0 + c4), &Ws[r][c4]);
    }
    __syncthreads();
    bf16x8 a[4], b[4];
#pragma unroll
    for (int m = 0; m < 4; ++m)
      a[m] = *reinterpret_cast<const bf16x8*>(&As[wr * 64 + m * 16 + l15][kg * 8]);
#pragma unroll
    for (int n = 0; n < 4; ++n)
      b[n] = *reinterpret_cast<const bf16x8*>(&Ws[wc * 64 + n * 16 + l15][kg * 8]);
#pragma unroll
    for (int m = 0; m < 4; ++m)
#pragma unroll
      for (int n = 0; n < 4; ++n)
        acc[m][n] = __builtin_amdgcn_mfma_f32_16x16x32_bf16(a[m], b[n], acc[m][n], 0, 0, 0);
    __syncthreads();
  }
  // C/D layout: col = lane&15, row = (lane>>4)*4 + reg  [m89 verified]
#pragma unroll
  for (int m = 0; m < 4; ++m) {
    const int row0 = rowBase + wr * 64 + m * 16 + kg * 4;
#pragma unroll
    for (int n = 0; n < 4; ++n) {
      const int col = colBase + wc * 64 + n * 16 + l15;
#pragma unroll
      for (int r = 0; r < 4; ++r) C[(size_t)(row0 + r) * N + col] = acc[m][n][r];
    }
  }
}

// One wave per 128-elem head row. Lane l owns d=l and d=l+64 (rotate_half is lane-local).
// q: RMSNorm + RoPE + *SCALE -> q_b [B][H][T][D]
// k: RMSNorm + RoPE          -> k_b [B][HKV][T][D]
// v: cast only               -> vt_b [B][HKV][D][T]  (transposed for PV B-operand)
__global__ __launch_bounds__(256) void norm_rope_cvt(
    const float* __restrict__ q_proj, const float* __restrict__ k_proj,
    const float* __restrict__ v_proj, const float* __restrict__ cosb,
    const float* __restrict__ sinb, const float* __restrict__ q_nw,
    const float* __restrict__ k_nw, u16* __restrict__ q_b,
    u16* __restrict__ k_b, u16* __restrict__ vt_b) {
  const int gwave = (int)((blockIdx.x * 256 + threadIdx.x) >> 6);
  const int lane = threadIdx.x & 63;
  const int NQ = B_ * T_ * H_;    // 49152
  const int NK = B_ * T_ * HKV_;  // 8192
  if (gwave < NQ) {
    const int bt = gwave / H_, h = gwave - bt * H_;
    const float* src = q_proj + (size_t)bt * (H_ * D_) + h * D_;
    const float x1 = src[lane], x2 = src[lane + 64];
    float ss = x1 * x1 + x2 * x2;
#pragma unroll
    for (int m = 32; m >= 1; m >>= 1) ss += __shfl_xor(ss, m);
    const float rinv = rsqrtf(ss * (1.0f / D_) + 1e-6f);
    const float c1 = cosb[(size_t)bt * D_ + lane], c2 = cosb[(size_t)bt * D_ + lane + 64];
    const float s1 = sinb[(size_t)bt * D_ + lane], s2 = sinb[(size_t)bt * D_ + lane + 64];
    const float n1 = x1 * rinv * q_nw[lane], n2 = x2 * rinv * q_nw[lane + 64];
    const float o1 = (n1 * c1 - n2 * s1) * SCALE_;
    const float o2 = (n2 * c2 + n1 * s2) * SCALE_;
    const int b = bt >> 11, t = bt & (T_ - 1);
    u16* dst = q_b + ((size_t)(b * H_ + h) * T_ + t) * D_;
    dst[lane] = f2b(o1);
    dst[lane + 64] = f2b(o2);
  } else if (gwave < NQ + NK) {
    const int r = gwave - NQ;
    const int bt = r >> 1, hv = r & 1;
    const float* src = k_proj + (size_t)bt * (HKV_ * D_) + hv * D_;
    const float x1 = src[lane], x2 = src[lane + 64];
    float ss = x1 * x1 + x2 * x2;
#pragma unroll
    for (int m = 32; m >= 1; m >>= 1) ss += __shfl_xor(ss, m);
    const float rinv = rsqrtf(ss * (1.0f / D_) + 1e-6f);
    const float c1 = cosb[(size_t)bt * D_ + lane], c2 = cosb[(size_t)bt * D_ + lane + 64];
    const float s1 = sinb[(size_t)bt * D_ + lane], s2 = sinb[(size_t)bt * D_ + lane + 64];
    const float n1 = x1 * rinv * k_nw[lane], n2 = x2 * rinv * k_nw[lane + 64];
    const float o1 = n1 * c1 - n2 * s1;
    const float o2 = n2 * c2 + n1 * s2;
    const int b = bt >> 11, t = bt & (T_ - 1);
    u16* dst = k_b + ((size_t)(b * HKV_ + hv) * T_ + t) * D_;
    dst[lane] = f2b(o1);
    dst[lane + 64] = f2b(o2);
  } else {
    const int r = gwave - NQ - NK;
    const int bt = r >> 1, hv = r & 1;
    const float* src = v_proj + (size_t)bt * (HKV_ * D_) + hv * D_;
    const float x1 = src[lane], x2 = src[lane + 64];
    const int b = bt >> 11, t = bt & (T_ - 1);
    u16* dst = vt_b + (size_t)(b * HKV_ + hv) * D_ * T_;
    dst[(size_t)lane * T_ + t] = f2b(x1);
    dst[(size_t)(lane + 64) * T_ + t] = f2b(x2);
  }
}

// Flash attention, causal, GQA. Block = 4 waves; block owns 64 q-rows (wave w: 16 rows).
// K/V read direct from global (512KB/head pair -> L2-resident). P re-laid out via LDS.
__global__ __launch_bounds__(256) void attn_kernel(const u16* __restrict__ q_b,
                                                   const u16* __restrict__ k_b,
                                                   const u16* __restrict__ vt_b,
                                                   u16* __restrict__ aout) {
  __shared__ u16 P_lds[64][80];  // 64q x 64k, +16 pad (16B-aligned rows)
  const int qt = blockIdx.x;   // q-tile (64 rows)
  const int bh = blockIdx.y;   // b*H + h
  const int b = bh / H_, h = bh - b * H_;
  const int kvh = h / GQ_;
  const int w = threadIdx.x >> 6;
  const int lane = threadIdx.x & 63;
  const int l15 = lane & 15, kg = lane >> 4;
  const int qbase = qt * 64;

  const u16* qrow = q_b + ((size_t)(b * H_ + h) * T_ + qbase + w * 16 + l15) * D_;
  bf16x8 qf[4];
#pragma unroll
  for (int s = 0; s < 4; ++s)
    qf[s] = *reinterpret_cast<const bf16x8*>(qrow + s * 32 + kg * 8);

  const f32x4 zero4 = {0.f, 0.f, 0.f, 0.f};
  f32x4 o[8];
#pragma unroll
  for (int n = 0; n < 8; ++n) o[n] = zero4;
  float mrow[4] = {-3e38f, -3e38f, -3e38f, -3e38f};
  float lsum[4] = {0.f, 0.f, 0.f, 0.f};

  const u16* Kb = k_b + (size_t)(b * HKV_ + kvh) * T_ * D_;
  const u16* Vb = vt_b + (size_t)(b * HKV_ + kvh) * D_ * T_;

  for (int kt = 0; kt <= qt; ++kt) {
    const int kb = kt * 64;
    f32x4 sc[4];
#pragma unroll
    for (int n = 0; n < 4; ++n) sc[n] = zero4;
#pragma unroll
    for (int n = 0; n < 4; ++n) {
      const u16* krow = Kb + (size_t)(kb + n * 16 + l15) * D_;
#pragma unroll
      for (int s = 0; s < 4; ++s) {
        bf16x8 kf = *reinterpret_cast<const bf16x8*>(krow + s * 32 + kg * 8);
        sc[n] = __builtin_amdgcn_mfma_f32_16x16x32_bf16(qf[s], kf, sc[n], 0, 0, 0);
      }
    }
    if (kt == qt) {  // diagonal tile: mask k > q
#pragma unroll
      for (int n = 0; n < 4; ++n)
#pragma unroll
        for (int r = 0; r < 4; ++r)
          if (n * 16 + l15 > w * 16 + kg * 4 + r) sc[n][r] = -3e38f;
    }
    // online softmax: rows live on lanes sharing (lane>>4); reduce over low 4 lane bits
    float alpha[4];
#pragma unroll
    for (int r = 0; r < 4; ++r) {
      float v = fmaxf(fmaxf(sc[0][r], sc[1][r]), fmaxf(sc[2][r], sc[3][r]));
      v = fmaxf(v, __shfl_xor(v, 1));
      v = fmaxf(v, __shfl_xor(v, 2));
      v = fmaxf(v, __shfl_xor(v, 4));
      v = fmaxf(v, __shfl_xor(v, 8));
      const float mnew = fmaxf(mrow[r], v);
      alpha[r] = __expf(mrow[r] - mnew);
      mrow[r] = mnew;
    }
    float rs[4] = {0.f, 0.f, 0.f, 0.f};
#pragma unroll
    for (int n = 0; n < 4; ++n)
#pragma unroll
      for (int r = 0; r < 4; ++r) {
        const float p = __expf(sc[n][r] - mrow[r]);
        rs[r] += p;
        P_lds[w * 16 + kg * 4 + r][n * 16 + l15] = f2b(p);
      }
#pragma unroll
    for (int r = 0; r < 4; ++r) {
      float v = rs[r];
      v += __shfl_xor(v, 1);
      v += __shfl_xor(v, 2);
      v += __shfl_xor(v, 4);
      v += __shfl_xor(v, 8);
      lsum[r] = lsum[r] * alpha[r] + v;
    }
#pragma unroll
    for (int n = 0; n < 8; ++n)
#pragma unroll
      for (int r = 0; r < 4; ++r) o[n][r] *= alpha[r];
    // PV: A = P (wave-private LDS rows), B = V^T rows (contiguous in k)
#pragma unroll
    for (int ks = 0; ks < 2; ++ks) {
      bf16x8 pf = *reinterpret_cast<const bf16x8*>(&P_lds[w * 16 + l15][ks * 32 + kg * 8]);
#pragma unroll
      for (int n = 0; n < 8; ++n) {
        const u16* vrow = Vb + (size_t)(n * 16 + l15) * T_ + kb + ks * 32 + kg * 8;
        bf16x8 vf = *reinterpret_cast<const bf16x8*>(vrow);
        o[n] = __builtin_amdgcn_mfma_f32_16x16x32_bf16(pf, vf, o[n], 0, 0, 0);
      }
    }
  }
  const int t0 = qbase + w * 16 + kg * 4;
#pragma unroll
  for (int n = 0; n < 8; ++n)
#pragma unroll
    for (int r = 0; r < 4; ++r)
      aout[(size_t)(b * T_ + t0 + r) * (H_ * D_) + h * D_ + n * 16 + l15] =
          f2b(o[n][r] / lsum[r]);
}

extern "C" void kernel_launch(void* const* d_in, const int* in_sizes, int n_in,
                              void* d_out, int out_size, void* d_ws, size_t ws_size,
                              hipStream_t stream) {
  const float* hidden = (const float*)d_in[0];
  const float* cosb   = (const float*)d_in[1];
  const float* sinb   = (const float*)d_in[2];
  // d_in[3] = attention_mask (pure causal; implemented analytically)
  const float* q_w  = (const float*)d_in[4];
  const float* k_w  = (const float*)d_in[5];
  const float* v_w  = (const float*)d_in[6];
  const float* o_w  = (const float*)d_in[7];
  const float* q_nw = (const float*)d_in[8];
  const float* k_nw = (const float*)d_in[9];
  float* out = (float*)d_out;

  // workspace layout (36 MiB total); d_out doubles as fp32 q_proj scratch (exact size)
  char* ws = (char*)d_ws;
  float* k_proj = (float*)(ws);                       // 4 MiB
  float* v_proj = (float*)(ws + (4u << 20));          // 4 MiB
  u16* q_b      = (u16*)(ws + (8u << 20));            // 12 MiB
  u16* k_b      = (u16*)(ws + (20u << 20));           // 2 MiB
  u16* vt_b     = (u16*)(ws + (22u << 20));           // 2 MiB
  u16* aout     = (u16*)(ws + (24u << 20));           // 12 MiB
  float* q_proj = out;

  const dim3 blk(256);
  const int M = B_ * T_;  // 4096
  gemm_bt<float><<<dim3(HID_ / 128, M / 128), blk, 0, stream>>>(hidden, q_w, q_proj, M, HID_, HID_);
  gemm_bt<float><<<dim3((HKV_ * D_) / 128, M / 128), blk, 0, stream>>>(hidden, k_w, k_proj, M, HKV_ * D_, HID_);
  gemm_bt<float><<<dim3((HKV_ * D_) / 128, M / 128), blk, 0, stream>>>(hidden, v_w, v_proj, M, HKV_ * D_, HID_);

  // 65536 row-waves total (q:49152, k:8192, v:8192) = 16384 blocks x 4 waves
  norm_rope_cvt<<<16384, 256, 0, stream>>>(q_proj, k_proj, v_proj, cosb, sinb,
                                           q_nw, k_nw, q_b, k_b, vt_b);

  attn_kernel<<<dim3(T_ / 64, B_ * H_), blk, 0, stream>>>(q_b, k_b, vt_b, aout);

  gemm_bt<u16><<<dim3(HID_ / 128, M / 128), blk, 0, stream>>>(aout, o_w, out, M, HID_, HID_);
}

// Round 2
// 306.062 us; speedup vs baseline: 1.9226x; 1.9226x over previous
//
#include <hip/hip_runtime.h>
#include <hip/hip_bf16.h>

// Qwen3 attention block, bf16-MFMA pipeline, round 2.
// B=2 T=2048 HID=1536 H=12 HKV=2 D=128. All I/O fp32; internal compute bf16.

#define B_   2
#define T_   2048
#define HID_ 1536
#define H_   12
#define HKV_ 2
#define D_   128
#define GQ_  (H_ / HKV_)
#define SCALE_ 0.08838834764831845f  // 1/sqrt(128), folded into Q at cast time

typedef unsigned short u16;
typedef __attribute__((ext_vector_type(4))) float f32x4;
typedef __attribute__((ext_vector_type(8))) short bf16x8;
typedef __attribute__((ext_vector_type(4))) unsigned short u16x4;
typedef __attribute__((ext_vector_type(8))) unsigned short u16x8;

__device__ __forceinline__ u16 f2b(float f) {
  union { __hip_bfloat16 h; u16 u; } cv;
  cv.h = __float2bfloat16(f);   // RNE
  return cv.u;
}

// ---------------- fp32 -> bf16 convert (vectorized, grid-stride) ----------------
__global__ __launch_bounds__(256) void cvt_f32_bf16(const float* __restrict__ src,
                                                    u16* __restrict__ dst, int n4) {
  int i = blockIdx.x * 256 + threadIdx.x;
  const int stride = gridDim.x * 256;
  for (; i < n4; i += stride) {
    const float4 v = reinterpret_cast<const float4*>(src)[i];
    u16x4 o = {f2b(v.x), f2b(v.y), f2b(v.z), f2b(v.w)};
    reinterpret_cast<u16x4*>(dst)[i] = o;
  }
}

// ---------------- bf16 GEMM: C[M][N] = A[M][K] * W[N][K]^T (fp32 out) ----------------
// 128x128 tile, BK=32, 4 waves 2x2, each wave 64x64 = 4x4 MFMA frags.
__global__ __launch_bounds__(256) void gemm_bt(const u16* __restrict__ A,
                                               const u16* __restrict__ W,
                                               float* __restrict__ C,
                                               int M, int N, int K) {
  __shared__ __align__(16) u16 As[128][40];  // +8 pad: 80B rows, 16B aligned
  __shared__ __align__(16) u16 Ws[128][40];
  const int tid  = threadIdx.x;
  const int lane = tid & 63;
  const int wid  = tid >> 6;
  const int wr = wid >> 1, wc = wid & 1;
  const int l15 = lane & 15, kg = lane >> 4;
  const int rowBase = blockIdx.y * 128;
  const int colBase = blockIdx.x * 128;

  const f32x4 zero4 = {0.f, 0.f, 0.f, 0.f};
  f32x4 acc[4][4];
#pragma unroll
  for (int m = 0; m < 4; ++m)
#pragma unroll
    for (int n = 0; n < 4; ++n) acc[m][n] = zero4;

  for (int k0 = 0; k0 < K; k0 += 32) {
    // stage 128x32 of A and W: 512 chunks of 8 elems, 256 threads x 2
#pragma unroll
    for (int i = 0; i < 2; ++i) {
      const int s = tid + i * 256;
      const int r = s >> 2, c8 = (s & 3) << 3;
      *reinterpret_cast<u16x8*>(&As[r][c8]) =
          *reinterpret_cast<const u16x8*>(A + (size_t)(rowBase + r) * K + k0 + c8);
      *reinterpret_cast<u16x8*>(&Ws[r][c8]) =
          *reinterpret_cast<const u16x8*>(W + (size_t)(colBase + r) * K + k0 + c8);
    }
    __syncthreads();
    bf16x8 a[4], b[4];
#pragma unroll
    for (int m = 0; m < 4; ++m)
      a[m] = *reinterpret_cast<const bf16x8*>(&As[wr * 64 + m * 16 + l15][kg * 8]);
#pragma unroll
    for (int n = 0; n < 4; ++n)
      b[n] = *reinterpret_cast<const bf16x8*>(&Ws[wc * 64 + n * 16 + l15][kg * 8]);
#pragma unroll
    for (int m = 0; m < 4; ++m)
#pragma unroll
      for (int n = 0; n < 4; ++n)
        acc[m][n] = __builtin_amdgcn_mfma_f32_16x16x32_bf16(a[m], b[n], acc[m][n], 0, 0, 0);
    __syncthreads();
  }
  // C/D layout: col = lane&15, row = (lane>>4)*4 + reg  [m89 verified]
#pragma unroll
  for (int m = 0; m < 4; ++m) {
    const int row0 = rowBase + wr * 64 + m * 16 + kg * 4;
#pragma unroll
    for (int n = 0; n < 4; ++n) {
      const int col = colBase + wc * 64 + n * 16 + l15;
#pragma unroll
      for (int r = 0; r < 4; ++r) C[(size_t)(row0 + r) * N + col] = acc[m][n][r];
    }
  }
}

// ---------------- RMSNorm + RoPE + cast ----------------
// One wave per 128-elem head row. Lane l owns d=l and d=l+64 (rotate_half lane-local).
__global__ __launch_bounds__(256) void norm_rope_cvt(
    const float* __restrict__ q_proj, const float* __restrict__ k_proj,
    const float* __restrict__ v_proj, const float* __restrict__ cosb,
    const float* __restrict__ sinb, const float* __restrict__ q_nw,
    const float* __restrict__ k_nw, u16* __restrict__ q_b,
    u16* __restrict__ k_b, u16* __restrict__ vt_b) {
  const int gwave = (int)((blockIdx.x * 256 + threadIdx.x) >> 6);
  const int lane = threadIdx.x & 63;
  const int NQ = B_ * T_ * H_;    // 49152
  const int NK = B_ * T_ * HKV_;  // 8192
  if (gwave < NQ) {
    const int bt = gwave / H_, h = gwave - bt * H_;
    const float* src = q_proj + (size_t)bt * (H_ * D_) + h * D_;
    const float x1 = src[lane], x2 = src[lane + 64];
    float ss = x1 * x1 + x2 * x2;
#pragma unroll
    for (int m = 32; m >= 1; m >>= 1) ss += __shfl_xor(ss, m);
    const float rinv = rsqrtf(ss * (1.0f / D_) + 1e-6f);
    const float c1 = cosb[(size_t)bt * D_ + lane], c2 = cosb[(size_t)bt * D_ + lane + 64];
    const float s1 = sinb[(size_t)bt * D_ + lane], s2 = sinb[(size_t)bt * D_ + lane + 64];
    const float n1 = x1 * rinv * q_nw[lane], n2 = x2 * rinv * q_nw[lane + 64];
    const float o1 = (n1 * c1 - n2 * s1) * SCALE_;
    const float o2 = (n2 * c2 + n1 * s2) * SCALE_;
    const int b = bt >> 11, t = bt & (T_ - 1);
    u16* dst = q_b + ((size_t)(b * H_ + h) * T_ + t) * D_;
    dst[lane] = f2b(o1);
    dst[lane + 64] = f2b(o2);
  } else if (gwave < NQ + NK) {
    const int r = gwave - NQ;
    const int bt = r >> 1, hv = r & 1;
    const float* src = k_proj + (size_t)bt * (HKV_ * D_) + hv * D_;
    const float x1 = src[lane], x2 = src[lane + 64];
    float ss = x1 * x1 + x2 * x2;
#pragma unroll
    for (int m = 32; m >= 1; m >>= 1) ss += __shfl_xor(ss, m);
    const float rinv = rsqrtf(ss * (1.0f / D_) + 1e-6f);
    const float c1 = cosb[(size_t)bt * D_ + lane], c2 = cosb[(size_t)bt * D_ + lane + 64];
    const float s1 = sinb[(size_t)bt * D_ + lane], s2 = sinb[(size_t)bt * D_ + lane + 64];
    const float n1 = x1 * rinv * k_nw[lane], n2 = x2 * rinv * k_nw[lane + 64];
    const float o1 = n1 * c1 - n2 * s1;
    const float o2 = n2 * c2 + n1 * s2;
    const int b = bt >> 11, t = bt & (T_ - 1);
    u16* dst = k_b + ((size_t)(b * HKV_ + hv) * T_ + t) * D_;
    dst[lane] = f2b(o1);
    dst[lane + 64] = f2b(o2);
  } else {
    const int r = gwave - NQ - NK;
    const int bt = r >> 1, hv = r & 1;
    const float* src = v_proj + (size_t)bt * (HKV_ * D_) + hv * D_;
    const float x1 = src[lane], x2 = src[lane + 64];
    const int b = bt >> 11, t = bt & (T_ - 1);
    u16* dst = vt_b + (size_t)(b * HKV_ + hv) * D_ * T_;
    dst[(size_t)lane * T_ + t] = f2b(x1);
    dst[(size_t)(lane + 64) * T_ + t] = f2b(x2);
  }
}

// ---------------- Flash attention, causal, GQA ----------------
// Block = 4 waves, 64 q-rows (wave w: rows w*16..+15). K/V tiles staged in LDS
// (shared by all waves), reg-staged with XOR-swizzled ds_write; next tile's
// global loads issued before compute (T14 async-stage split).
// K LDS:  elem(row,d)  = row*128 + (d ^ (row<<3))            [row = k mod 64, 4-way reads]
// V LDS:  elem(d,kk)   = (d>>1)*128 + ((((d&1)<<6)|kk) ^ (((d>>1)&15)<<3))
__global__ __launch_bounds__(256) void attn_kernel(const u16* __restrict__ q_b,
                                                   const u16* __restrict__ k_b,
                                                   const u16* __restrict__ vt_b,
                                                   u16* __restrict__ aout) {
  __shared__ __align__(16) u16 Ks[64 * 128];
  __shared__ __align__(16) u16 Vs[64 * 128];
  __shared__ __align__(16) u16 P_lds[64][80];
  const int bh = blockIdx.x;  // 0..23  (inner dim -> co-resident blocks mix qt)
  const int qt = blockIdx.y;  // 0..31
  const int b = bh / H_, h = bh - b * H_;
  const int kvh = h / GQ_;
  const int tid = threadIdx.x;
  const int w = tid >> 6, lane = tid & 63;
  const int l15 = lane & 15, kg = lane >> 4;
  const int qbase = qt * 64;

  const u16* Kb = k_b + (size_t)(b * HKV_ + kvh) * T_ * D_;
  const u16* Vb = vt_b + (size_t)(b * HKV_ + kvh) * D_ * T_;

  // Q fragments (16 q-rows per wave)
  const u16* qrow = q_b + ((size_t)(b * H_ + h) * T_ + qbase + w * 16 + l15) * D_;
  bf16x8 qf[4];
#pragma unroll
  for (int s = 0; s < 4; ++s)
    qf[s] = *reinterpret_cast<const bf16x8*>(qrow + s * 32 + kg * 8);

  // staging thread-constants (4 chunks of 16B per tile per thread)
  const int krow0 = tid >> 4;           // +16 per chunk
  const int kcol8 = (tid & 15) << 3;
  const int kdst0 = krow0 * 128 + (kcol8 ^ (krow0 << 3));  // +2048 per chunk
  const u16* ksrc0 = Kb + (size_t)krow0 * D_ + kcol8;      // +kb*D_, +2048 per chunk

  const int vd0 = tid >> 3;             // +32 per chunk
  const int vkk0 = (tid & 7) << 3;
  const int vdst0 = (vd0 >> 1) * 128 + ((((vd0 & 1) << 6) | vkk0) ^ ((vd0 >> 1) << 3));
  const u16* vsrc0 = Vb + (size_t)vd0 * T_ + vkk0;         // +kb, +32*T_ per chunk

  // fragment read offsets
  int koff[4];
#pragma unroll
  for (int s = 0; s < 4; ++s) koff[s] = (s * 32 + kg * 8) ^ (l15 << 3);
  const int kbase = l15 * 128;
  int voff[2][2];
#pragma unroll
  for (int p = 0; p < 2; ++p)
#pragma unroll
    for (int ks = 0; ks < 2; ++ks)
      voff[p][ks] = (((l15 & 1) << 6) | (ks * 32) | (kg * 8)) ^ (((p << 3) | (l15 >> 1)) << 3);
  const int vrowb = (l15 >> 1) * 128;

  u16x8 kpre[4], vpre[4];
#pragma unroll
  for (int c = 0; c < 4; ++c) {
    kpre[c] = *reinterpret_cast<const u16x8*>(ksrc0 + c * 2048);
    vpre[c] = *reinterpret_cast<const u16x8*>(vsrc0 + (size_t)c * 32 * T_);
  }

  const f32x4 zero4 = {0.f, 0.f, 0.f, 0.f};
  f32x4 o[8];
#pragma unroll
  for (int n = 0; n < 8; ++n) o[n] = zero4;
  float mrow[4] = {-3e38f, -3e38f, -3e38f, -3e38f};
  float lsum[4] = {0.f, 0.f, 0.f, 0.f};

  for (int kt = 0; kt <= qt; ++kt) {
    __syncthreads();  // previous tile fully consumed
#pragma unroll
    for (int c = 0; c < 4; ++c) {
      *reinterpret_cast<u16x8*>(&Ks[kdst0 + c * 2048]) = kpre[c];
      *reinterpret_cast<u16x8*>(&Vs[vdst0 + c * 2048]) = vpre[c];
    }
    __syncthreads();  // tile ready
    if (kt < qt) {    // issue next tile's loads; latency hides under compute
      const size_t kadv = (size_t)(kt + 1) * 64;
#pragma unroll
      for (int c = 0; c < 4; ++c) {
        kpre[c] = *reinterpret_cast<const u16x8*>(ksrc0 + kadv * D_ + c * 2048);
        vpre[c] = *reinterpret_cast<const u16x8*>(vsrc0 + kadv + (size_t)c * 32 * T_);
      }
    }
    // QK^T from LDS
    f32x4 sc[4];
#pragma unroll
    for (int n = 0; n < 4; ++n) sc[n] = zero4;
#pragma unroll
    for (int n = 0; n < 4; ++n)
#pragma unroll
      for (int s = 0; s < 4; ++s) {
        bf16x8 kf = *reinterpret_cast<const bf16x8*>(&Ks[n * 2048 + kbase + koff[s]]);
        sc[n] = __builtin_amdgcn_mfma_f32_16x16x32_bf16(qf[s], kf, sc[n], 0, 0, 0);
      }
    if (kt == qt) {  // diagonal tile: mask k > q
#pragma unroll
      for (int n = 0; n < 4; ++n)
#pragma unroll
        for (int r = 0; r < 4; ++r)
          if (n * 16 + l15 > w * 16 + kg * 4 + r) sc[n][r] = -3e38f;
    }
    // online softmax: rows on lanes sharing (lane>>4); reduce over low 4 lane bits
    float alpha[4];
#pragma unroll
    for (int r = 0; r < 4; ++r) {
      float v = fmaxf(fmaxf(sc[0][r], sc[1][r]), fmaxf(sc[2][r], sc[3][r]));
      v = fmaxf(v, __shfl_xor(v, 1));
      v = fmaxf(v, __shfl_xor(v, 2));
      v = fmaxf(v, __shfl_xor(v, 4));
      v = fmaxf(v, __shfl_xor(v, 8));
      const float mnew = fmaxf(mrow[r], v);
      alpha[r] = __expf(mrow[r] - mnew);
      mrow[r] = mnew;
    }
    float rs[4] = {0.f, 0.f, 0.f, 0.f};
#pragma unroll
    for (int n = 0; n < 4; ++n)
#pragma unroll
      for (int r = 0; r < 4; ++r) {
        const float p = __expf(sc[n][r] - mrow[r]);
        rs[r] += p;
        P_lds[w * 16 + kg * 4 + r][n * 16 + l15] = f2b(p);
      }
#pragma unroll
    for (int r = 0; r < 4; ++r) {
      float v = rs[r];
      v += __shfl_xor(v, 1);
      v += __shfl_xor(v, 2);
      v += __shfl_xor(v, 4);
      v += __shfl_xor(v, 8);
      lsum[r] = lsum[r] * alpha[r] + v;
    }
#pragma unroll
    for (int n = 0; n < 8; ++n)
#pragma unroll
      for (int r = 0; r < 4; ++r) o[n][r] *= alpha[r];
    // PV from LDS
#pragma unroll
    for (int ks = 0; ks < 2; ++ks) {
      bf16x8 pf = *reinterpret_cast<const bf16x8*>(&P_lds[w * 16 + l15][ks * 32 + kg * 8]);
#pragma unroll
      for (int n = 0; n < 8; ++n) {
        bf16x8 vf = *reinterpret_cast<const bf16x8*>(&Vs[n * 1024 + vrowb + voff[n & 1][ks]]);
        o[n] = __builtin_amdgcn_mfma_f32_16x16x32_bf16(pf, vf, o[n], 0, 0, 0);
      }
    }
  }
  float inv[4];
#pragma unroll
  for (int r = 0; r < 4; ++r) inv[r] = 1.0f / lsum[r];
  const int t0 = qbase + w * 16 + kg * 4;
#pragma unroll
  for (int n = 0; n < 8; ++n)
#pragma unroll
    for (int r = 0; r < 4; ++r)
      aout[(size_t)(b * T_ + t0 + r) * (H_ * D_) + h * D_ + n * 16 + l15] =
          f2b(o[n][r] * inv[r]);
}

extern "C" void kernel_launch(void* const* d_in, const int* in_sizes, int n_in,
                              void* d_out, int out_size, void* d_ws, size_t ws_size,
                              hipStream_t stream) {
  const float* hidden = (const float*)d_in[0];
  const float* cosb   = (const float*)d_in[1];
  const float* sinb   = (const float*)d_in[2];
  // d_in[3] = attention_mask (pure causal; implemented analytically)
  const float* q_w  = (const float*)d_in[4];
  const float* k_w  = (const float*)d_in[5];
  const float* v_w  = (const float*)d_in[6];
  const float* o_w  = (const float*)d_in[7];
  const float* q_nw = (const float*)d_in[8];
  const float* k_nw = (const float*)d_in[9];
  float* out = (float*)d_out;

  // workspace layout (34.5 MiB peak; 36 MiB proven available). Overlaps are
  // phase-disjoint: hidden_b dies after v-gemm (q_b overwrites); k/v_proj+qwb
  // die after norm_rope/q-gemm (aout overwrites).
  char* ws = (char*)d_ws;
  const size_t MB = 1u << 20;
  u16*   hidden_b = (u16*)(ws);                  // [0,12)   -> later q_b
  float* k_proj   = (float*)(ws + 12 * MB);      // [12,16)
  float* v_proj   = (float*)(ws + 16 * MB);      // [16,20)
  u16*   qwb      = (u16*)(ws + 20 * MB);        // [20,24.5)
  u16*   kwb      = (u16*)(ws + 24 * MB + MB / 2);   // [24.5,25.25)
  u16*   vwb      = (u16*)(ws + 25 * MB + MB / 4);   // [25.25,26)
  u16*   k_b      = (u16*)(ws + 26 * MB);        // [26,28)
  u16*   vt_b     = (u16*)(ws + 28 * MB);        // [28,30)
  u16*   owb      = (u16*)(ws + 30 * MB);        // [30,34.5)
  u16*   aout     = (u16*)(ws + 12 * MB);        // [12,24)  (phase 2)
  u16*   q_b      = hidden_b;                    // [0,12)   (phase 2)
  float* q_proj   = out;                         // d_out as fp32 scratch

  const dim3 blk(256);
  const int M = B_ * T_;  // 4096

  // fp32 -> bf16 converts
  {
    const int nh = (B_ * T_ * HID_) / 4;                 // 1572864
    const int nq = (H_ * D_ * HID_) / 4;                 // 589824
    const int nk = (HKV_ * D_ * HID_) / 4;               // 98304
    cvt_f32_bf16<<<2048, blk, 0, stream>>>(hidden, hidden_b, nh);
    cvt_f32_bf16<<<2048, blk, 0, stream>>>(q_w, qwb, nq);
    cvt_f32_bf16<<<(nk + 255) / 256, blk, 0, stream>>>(k_w, kwb, nk);
    cvt_f32_bf16<<<(nk + 255) / 256, blk, 0, stream>>>(v_w, vwb, nk);
    cvt_f32_bf16<<<2048, blk, 0, stream>>>(o_w, owb, nq);
  }

  gemm_bt<<<dim3(HID_ / 128, M / 128), blk, 0, stream>>>(hidden_b, qwb, q_proj, M, HID_, HID_);
  gemm_bt<<<dim3((HKV_ * D_) / 128, M / 128), blk, 0, stream>>>(hidden_b, kwb, k_proj, M, HKV_ * D_, HID_);
  gemm_bt<<<dim3((HKV_ * D_) / 128, M / 128), blk, 0, stream>>>(hidden_b, vwb, v_proj, M, HKV_ * D_, HID_);

  norm_rope_cvt<<<16384, blk, 0, stream>>>(q_proj, k_proj, v_proj, cosb, sinb,
                                           q_nw, k_nw, q_b, k_b, vt_b);

  attn_kernel<<<dim3(B_ * H_, T_ / 64), blk, 0, stream>>>(q_b, k_b, vt_b, aout);

  gemm_bt<<<dim3(HID_ / 128, M / 128), blk, 0, stream>>>(aout, owb, out, M, HID_, HID_);
}

// Round 3
// 216.058 us; speedup vs baseline: 2.7235x; 1.4166x over previous
//
#include <hip/hip_runtime.h>
#include <hip/hip_bf16.h>

// Qwen3 attention block, bf16-MFMA pipeline, round 3.
// B=2 T=2048 HID=1536 H=12 HKV=2 D=128. All I/O fp32; internal compute bf16.

#define B_   2
#define T_   2048
#define HID_ 1536
#define H_   12
#define HKV_ 2
#define D_   128
#define GQ_  (H_ / HKV_)
#define NQKV_ 2048   // fused projection width: 1536 q + 256 k + 256 v
#define SCALE_ 0.08838834764831845f  // 1/sqrt(128), folded into Q at cast time

typedef unsigned short u16;
typedef __attribute__((ext_vector_type(4))) float f32x4;
typedef __attribute__((ext_vector_type(8))) short bf16x8;
typedef __attribute__((ext_vector_type(4))) unsigned short u16x4;
typedef __attribute__((ext_vector_type(8))) unsigned short u16x8;

__device__ __forceinline__ u16 f2b(float f) {
  union { __hip_bfloat16 h; u16 u; } cv;
  cv.h = __float2bfloat16(f);   // RNE
  return cv.u;
}
__device__ __forceinline__ float b2f(u16 u) {
  union { float f; unsigned i; } cv;
  cv.i = ((unsigned)u) << 16;
  return cv.f;
}

// async global->LDS, 16B per lane; LDS dest = wave-uniform base + lane*16
__device__ __forceinline__ void glds16(const u16* g, u16* l) {
  __builtin_amdgcn_global_load_lds((const __attribute__((address_space(1))) void*)g,
                                   (__attribute__((address_space(3))) void*)l, 16, 0, 0);
}

// ---------------- fp32 -> bf16 convert (vectorized, grid-stride) ----------------
__global__ __launch_bounds__(256) void cvt_f32_bf16(const float* __restrict__ src,
                                                    u16* __restrict__ dst, int n4) {
  int i = blockIdx.x * 256 + threadIdx.x;
  const int stride = gridDim.x * 256;
  for (; i < n4; i += stride) {
    const float4 v = reinterpret_cast<const float4*>(src)[i];
    u16x4 o = {f2b(v.x), f2b(v.y), f2b(v.z), f2b(v.w)};
    reinterpret_cast<u16x4*>(dst)[i] = o;
  }
}

// ---------------- bf16 GEMM (m97 structure): C[M][N] = A[M][K] * W[N][K]^T ----------------
// 128x128 tile, BK=32, 4 waves 2x2, linear LDS + global_load_lds width-16 staging.
__device__ __forceinline__ void cstore(float* p, float v) { *p = v; }
__device__ __forceinline__ void cstore(u16* p, float v) { *p = f2b(v); }

template <typename CT>
__global__ __launch_bounds__(256) void gemm_bt(const u16* __restrict__ A,
                                               const u16* __restrict__ W,
                                               CT* __restrict__ C,
                                               int M, int N, int K) {
  __shared__ __align__(16) u16 As[128 * 32];  // linear: row r at u16 offset r*32
  __shared__ __align__(16) u16 Ws[128 * 32];
  const int tid  = threadIdx.x;
  const int lane = tid & 63;
  const int wid  = tid >> 6;
  const int wr = wid >> 1, wc = wid & 1;
  const int l15 = lane & 15, kg = lane >> 4;
  const int rowBase = blockIdx.y * 128;
  const int colBase = blockIdx.x * 128;

  // staging: chunk c = 16 rows; wave w stages chunks w and w+4 (1KB each)
  const int srow = lane >> 2;           // 0..15
  const int scol = (lane & 3) << 3;     // u16 col 0/8/16/24
  const u16* Ab = A + (size_t)(rowBase + wid * 16 + srow) * K + scol;
  const u16* Wb = W + (size_t)(colBase + wid * 16 + srow) * K + scol;
  u16* AsW = &As[wid * 512];
  u16* WsW = &Ws[wid * 512];

  const f32x4 zero4 = {0.f, 0.f, 0.f, 0.f};
  f32x4 acc[4][4];
#pragma unroll
  for (int m = 0; m < 4; ++m)
#pragma unroll
    for (int n = 0; n < 4; ++n) acc[m][n] = zero4;

  for (int k0 = 0; k0 < K; k0 += 32) {
    __syncthreads();  // prev tile's ds_reads done (WAR)
    glds16(Ab + k0, AsW);
    glds16(Ab + (size_t)64 * K + k0, AsW + 2048);
    glds16(Wb + k0, WsW);
    glds16(Wb + (size_t)64 * K + k0, WsW + 2048);
    __syncthreads();  // drains vmcnt: tile ready
    bf16x8 a[4], b[4];
#pragma unroll
    for (int m = 0; m < 4; ++m)
      a[m] = *reinterpret_cast<const bf16x8*>(&As[(wr * 64 + m * 16 + l15) * 32 + kg * 8]);
#pragma unroll
    for (int n = 0; n < 4; ++n)
      b[n] = *reinterpret_cast<const bf16x8*>(&Ws[(wc * 64 + n * 16 + l15) * 32 + kg * 8]);
#pragma unroll
    for (int m = 0; m < 4; ++m)
#pragma unroll
      for (int n = 0; n < 4; ++n)
        acc[m][n] = __builtin_amdgcn_mfma_f32_16x16x32_bf16(a[m], b[n], acc[m][n], 0, 0, 0);
  }
  // C/D layout: col = lane&15, row = (lane>>4)*4 + reg  [m89 verified]
#pragma unroll
  for (int m = 0; m < 4; ++m) {
    const int row0 = rowBase + wr * 64 + m * 16 + kg * 4;
#pragma unroll
    for (int n = 0; n < 4; ++n) {
      const int col = colBase + wc * 64 + n * 16 + l15;
#pragma unroll
      for (int r = 0; r < 4; ++r) cstore(&C[(size_t)(row0 + r) * N + col], acc[m][n][r]);
    }
  }
}

// ---------------- RMSNorm + RoPE + cast (reads fused bf16 qkv_proj) ----------------
// One wave per 128-elem head row. Lane l owns d=l and d=l+64 (rotate_half lane-local).
__global__ __launch_bounds__(256) void norm_rope_cvt(
    const u16* __restrict__ qkv, const float* __restrict__ cosb,
    const float* __restrict__ sinb, const float* __restrict__ q_nw,
    const float* __restrict__ k_nw, u16* __restrict__ q_b,
    u16* __restrict__ k_b, u16* __restrict__ vt_b) {
  const int gwave = (int)((blockIdx.x * 256 + threadIdx.x) >> 6);
  const int lane = threadIdx.x & 63;
  const int NQ = B_ * T_ * H_;    // 49152
  const int NK = B_ * T_ * HKV_;  // 8192
  if (gwave < NQ) {
    const int bt = gwave / H_, h = gwave - bt * H_;
    const u16* src = qkv + (size_t)bt * NQKV_ + h * D_;
    const float x1 = b2f(src[lane]), x2 = b2f(src[lane + 64]);
    float ss = x1 * x1 + x2 * x2;
#pragma unroll
    for (int m = 32; m >= 1; m >>= 1) ss += __shfl_xor(ss, m);
    const float rinv = rsqrtf(ss * (1.0f / D_) + 1e-6f);
    const float c1 = cosb[(size_t)bt * D_ + lane], c2 = cosb[(size_t)bt * D_ + lane + 64];
    const float s1 = sinb[(size_t)bt * D_ + lane], s2 = sinb[(size_t)bt * D_ + lane + 64];
    const float n1 = x1 * rinv * q_nw[lane], n2 = x2 * rinv * q_nw[lane + 64];
    const float o1 = (n1 * c1 - n2 * s1) * SCALE_;
    const float o2 = (n2 * c2 + n1 * s2) * SCALE_;
    const int b = bt >> 11, t = bt & (T_ - 1);
    u16* dst = q_b + ((size_t)(b * H_ + h) * T_ + t) * D_;
    dst[lane] = f2b(o1);
    dst[lane + 64] = f2b(o2);
  } else if (gwave < NQ + NK) {
    const int r = gwave - NQ;
    const int bt = r >> 1, hv = r & 1;
    const u16* src = qkv + (size_t)bt * NQKV_ + 1536 + hv * D_;
    const float x1 = b2f(src[lane]), x2 = b2f(src[lane + 64]);
    float ss = x1 * x1 + x2 * x2;
#pragma unroll
    for (int m = 32; m >= 1; m >>= 1) ss += __shfl_xor(ss, m);
    const float rinv = rsqrtf(ss * (1.0f / D_) + 1e-6f);
    const float c1 = cosb[(size_t)bt * D_ + lane], c2 = cosb[(size_t)bt * D_ + lane + 64];
    const float s1 = sinb[(size_t)bt * D_ + lane], s2 = sinb[(size_t)bt * D_ + lane + 64];
    const float n1 = x1 * rinv * k_nw[lane], n2 = x2 * rinv * k_nw[lane + 64];
    const float o1 = n1 * c1 - n2 * s1;
    const float o2 = n2 * c2 + n1 * s2;
    const int b = bt >> 11, t = bt & (T_ - 1);
    u16* dst = k_b + ((size_t)(b * HKV_ + hv) * T_ + t) * D_;
    dst[lane] = f2b(o1);
    dst[lane + 64] = f2b(o2);
  } else {
    const int r = gwave - NQ - NK;
    const int bt = r >> 1, hv = r & 1;
    const u16* src = qkv + (size_t)bt * NQKV_ + 1792 + hv * D_;
    const float x1 = b2f(src[lane]), x2 = b2f(src[lane + 64]);
    const int b = bt >> 11, t = bt & (T_ - 1);
    u16* dst = vt_b + (size_t)(b * HKV_ + hv) * D_ * T_;
    dst[(size_t)lane * T_ + t] = f2b(x1);
    dst[(size_t)(lane + 64) * T_ + t] = f2b(x2);
  }
}

// ---------------- Flash attention, causal, GQA, split-K ----------------
// Block = 4 waves, 64 q-rows. blockIdx.y in [0,48): y<32 -> (qt=y, s=0);
// y>=32 -> (qt=y-16, s=1). s=0 covers kt 0..min(qt,15); s=1 covers kt 16..qt.
// qt<16: single block, writes normalized aout. qt>=16: two partial blocks
// (bf16 unnormalized o + {m,l} sidecar); combine kernel merges.
__global__ __launch_bounds__(256) void attn_kernel(const u16* __restrict__ q_b,
                                                   const u16* __restrict__ k_b,
                                                   const u16* __restrict__ vt_b,
                                                   u16* __restrict__ aout,
                                                   u16* __restrict__ po0,
                                                   float2* __restrict__ ml) {
  __shared__ __align__(16) u16 Ks[64 * 128];
  __shared__ __align__(16) u16 Vs[64 * 128];
  __shared__ __align__(16) u16 P_lds[64][80];
  const int bh = blockIdx.x;  // 0..23
  const int y = blockIdx.y;   // 0..47
  const int qt = (y < 32) ? y : y - 16;
  const int s = (y < 32) ? 0 : 1;
  const int kt0 = s * 16;
  const int ktend = (s == 0) ? min(qt, 15) : qt;
  const bool splitq = (qt >= 16);
  const int b = bh / H_, h = bh - b * H_;
  const int kvh = h / GQ_;
  const int tid = threadIdx.x;
  const int w = tid >> 6, lane = tid & 63;
  const int l15 = lane & 15, kg = lane >> 4;
  const int qbase = qt * 64;

  const u16* Kb = k_b + (size_t)(b * HKV_ + kvh) * T_ * D_;
  const u16* Vb = vt_b + (size_t)(b * HKV_ + kvh) * D_ * T_;

  // Q fragments (16 q-rows per wave)
  const u16* qrow = q_b + ((size_t)(b * H_ + h) * T_ + qbase + w * 16 + l15) * D_;
  bf16x8 qf[4];
#pragma unroll
  for (int ss = 0; ss < 4; ++ss)
    qf[ss] = *reinterpret_cast<const bf16x8*>(qrow + ss * 32 + kg * 8);

  // staging thread-constants (4 chunks of 16B per tile per thread)
  const int krow0 = tid >> 4;
  const int kcol8 = (tid & 15) << 3;
  const int kdst0 = krow0 * 128 + (kcol8 ^ (krow0 << 3));
  const u16* ksrc0 = Kb + (size_t)krow0 * D_ + kcol8;

  const int vd0 = tid >> 3;
  const int vkk0 = (tid & 7) << 3;
  const int vdst0 = (vd0 >> 1) * 128 + ((((vd0 & 1) << 6) | vkk0) ^ ((vd0 >> 1) << 3));
  const u16* vsrc0 = Vb + (size_t)vd0 * T_ + vkk0;

  // fragment read offsets
  int koff[4];
#pragma unroll
  for (int ss = 0; ss < 4; ++ss) koff[ss] = (ss * 32 + kg * 8) ^ (l15 << 3);
  const int kbase = l15 * 128;
  int voff[2][2];
#pragma unroll
  for (int p = 0; p < 2; ++p)
#pragma unroll
    for (int ks = 0; ks < 2; ++ks)
      voff[p][ks] = (((l15 & 1) << 6) | (ks * 32) | (kg * 8)) ^ (((p << 3) | (l15 >> 1)) << 3);
  const int vrowb = (l15 >> 1) * 128;

  u16x8 kpre[4], vpre[4];
#pragma unroll
  for (int c = 0; c < 4; ++c) {
    kpre[c] = *reinterpret_cast<const u16x8*>(ksrc0 + (size_t)kt0 * 64 * D_ + c * 2048);
    vpre[c] = *reinterpret_cast<const u16x8*>(vsrc0 + (size_t)kt0 * 64 + (size_t)c * 32 * T_);
  }

  const f32x4 zero4 = {0.f, 0.f, 0.f, 0.f};
  f32x4 o[8];
#pragma unroll
  for (int n = 0; n < 8; ++n) o[n] = zero4;
  float mrow[4] = {-3e38f, -3e38f, -3e38f, -3e38f};
  float lsum[4] = {0.f, 0.f, 0.f, 0.f};

  for (int kt = kt0; kt <= ktend; ++kt) {
    __syncthreads();  // previous tile fully consumed
#pragma unroll
    for (int c = 0; c < 4; ++c) {
      *reinterpret_cast<u16x8*>(&Ks[kdst0 + c * 2048]) = kpre[c];
      *reinterpret_cast<u16x8*>(&Vs[vdst0 + c * 2048]) = vpre[c];
    }
    __syncthreads();  // tile ready
    if (kt < ktend) {  // issue next tile's loads; latency hides under compute
      const size_t kadv = (size_t)(kt + 1) * 64;
#pragma unroll
      for (int c = 0; c < 4; ++c) {
        kpre[c] = *reinterpret_cast<const u16x8*>(ksrc0 + kadv * D_ + c * 2048);
        vpre[c] = *reinterpret_cast<const u16x8*>(vsrc0 + kadv + (size_t)c * 32 * T_);
      }
    }
    // QK^T from LDS
    f32x4 sc[4];
#pragma unroll
    for (int n = 0; n < 4; ++n) sc[n] = zero4;
#pragma unroll
    for (int n = 0; n < 4; ++n)
#pragma unroll
      for (int ss = 0; ss < 4; ++ss) {
        bf16x8 kf = *reinterpret_cast<const bf16x8*>(&Ks[n * 2048 + kbase + koff[ss]]);
        sc[n] = __builtin_amdgcn_mfma_f32_16x16x32_bf16(qf[ss], kf, sc[n], 0, 0, 0);
      }
    if (kt == qt) {  // diagonal tile: mask k > q
#pragma unroll
      for (int n = 0; n < 4; ++n)
#pragma unroll
        for (int r = 0; r < 4; ++r)
          if (n * 16 + l15 > w * 16 + kg * 4 + r) sc[n][r] = -3e38f;
    }
    // online softmax with defer-max (T13): rescale only if row max grows > 8
    float pmax[4];
#pragma unroll
    for (int r = 0; r < 4; ++r) {
      float v = fmaxf(fmaxf(sc[0][r], sc[1][r]), fmaxf(sc[2][r], sc[3][r]));
      v = fmaxf(v, __shfl_xor(v, 1));
      v = fmaxf(v, __shfl_xor(v, 2));
      v = fmaxf(v, __shfl_xor(v, 4));
      v = fmaxf(v, __shfl_xor(v, 8));
      pmax[r] = v;
    }
    const bool grow = (pmax[0] > mrow[0] + 8.f) | (pmax[1] > mrow[1] + 8.f) |
                      (pmax[2] > mrow[2] + 8.f) | (pmax[3] > mrow[3] + 8.f);
    if (__any(grow)) {
#pragma unroll
      for (int r = 0; r < 4; ++r) {
        const float mnew = fmaxf(mrow[r], pmax[r]);
        const float alpha = __expf(mrow[r] - mnew);
        mrow[r] = mnew;
        lsum[r] *= alpha;
#pragma unroll
        for (int n = 0; n < 8; ++n) o[n][r] *= alpha;
      }
    }
    float rs[4] = {0.f, 0.f, 0.f, 0.f};
#pragma unroll
    for (int n = 0; n < 4; ++n)
#pragma unroll
      for (int r = 0; r < 4; ++r) {
        const float p = __expf(sc[n][r] - mrow[r]);
        rs[r] += p;
        P_lds[w * 16 + kg * 4 + r][n * 16 + l15] = f2b(p);
      }
#pragma unroll
    for (int r = 0; r < 4; ++r) {
      float v = rs[r];
      v += __shfl_xor(v, 1);
      v += __shfl_xor(v, 2);
      v += __shfl_xor(v, 4);
      v += __shfl_xor(v, 8);
      lsum[r] += v;
    }
    // PV from LDS
#pragma unroll
    for (int ks = 0; ks < 2; ++ks) {
      bf16x8 pf = *reinterpret_cast<const bf16x8*>(&P_lds[w * 16 + l15][ks * 32 + kg * 8]);
#pragma unroll
      for (int n = 0; n < 8; ++n) {
        bf16x8 vf = *reinterpret_cast<const bf16x8*>(&Vs[n * 1024 + vrowb + voff[n & 1][ks]]);
        o[n] = __builtin_amdgcn_mfma_f32_16x16x32_bf16(pf, vf, o[n], 0, 0, 0);
      }
    }
  }

  const int t0 = qbase + w * 16 + kg * 4;
  if (!splitq) {
    float inv[4];
#pragma unroll
    for (int r = 0; r < 4; ++r) inv[r] = 1.0f / lsum[r];
#pragma unroll
    for (int n = 0; n < 8; ++n)
#pragma unroll
      for (int r = 0; r < 4; ++r)
        aout[(size_t)(b * T_ + t0 + r) * (H_ * D_) + h * D_ + n * 16 + l15] =
            f2b(o[n][r] * inv[r]);
  } else {
    const int slot = (bh << 4) + (qt - 16);
    if (l15 == 0) {
#pragma unroll
      for (int r = 0; r < 4; ++r) {
        const int row = w * 16 + kg * 4 + r;
        float2 v; v.x = mrow[r]; v.y = lsum[r];
        ml[(size_t)(slot * 2 + s) * 64 + row] = v;
      }
    }
    if (s == 1) {  // unnormalized partial into this q-tile's aout slot
#pragma unroll
      for (int n = 0; n < 8; ++n)
#pragma unroll
        for (int r = 0; r < 4; ++r)
          aout[(size_t)(b * T_ + t0 + r) * (H_ * D_) + h * D_ + n * 16 + l15] =
              f2b(o[n][r]);
    } else {       // unnormalized partial into scratch
#pragma unroll
      for (int n = 0; n < 8; ++n)
#pragma unroll
        for (int r = 0; r < 4; ++r)
          po0[((size_t)slot * 64 + w * 16 + kg * 4 + r) * 128 + n * 16 + l15] =
              f2b(o[n][r]);
    }
  }
}

// ---------------- combine split-K partials ----------------
__global__ __launch_bounds__(256) void combine_kernel(u16* __restrict__ aout,
                                                      const u16* __restrict__ po0,
                                                      const float2* __restrict__ ml) {
  const int bh = blockIdx.x;        // 0..23
  const int qt16 = blockIdx.y;      // 0..15 -> qt = 16+qt16
  const int slot = (bh << 4) + qt16;
  const int b = bh / H_, h = bh - b * H_;
  const int t0 = (qt16 + 16) * 64;
  const int tid = threadIdx.x;
  const int row = tid >> 2;
  const int colc = (tid & 3) << 5;  // 32-elem column chunk

  const float2 ml0 = ml[(size_t)(slot * 2 + 0) * 64 + row];
  const float2 ml1 = ml[(size_t)(slot * 2 + 1) * 64 + row];
  const float m = fmaxf(ml0.x, ml1.x);
  const float c0 = __expf(ml0.x - m), c1 = __expf(ml1.x - m);
  const float inv = 1.0f / (ml0.y * c0 + ml1.y * c1);
  const float s0 = c0 * inv, s1 = c1 * inv;

  const u16* p0 = po0 + ((size_t)slot * 64 + row) * 128 + colc;
  u16* a = aout + (size_t)(b * T_ + t0 + row) * (H_ * D_) + h * D_ + colc;
#pragma unroll
  for (int j = 0; j < 4; ++j) {
    u16x8 v0 = *reinterpret_cast<const u16x8*>(p0 + j * 8);
    u16x8 v1 = *reinterpret_cast<const u16x8*>(a + j * 8);
    u16x8 out;
#pragma unroll
    for (int e = 0; e < 8; ++e) out[e] = f2b(b2f(v0[e]) * s0 + b2f(v1[e]) * s1);
    *reinterpret_cast<u16x8*>(a + j * 8) = out;
  }
}

extern "C" void kernel_launch(void* const* d_in, const int* in_sizes, int n_in,
                              void* d_out, int out_size, void* d_ws, size_t ws_size,
                              hipStream_t stream) {
  const float* hidden = (const float*)d_in[0];
  const float* cosb   = (const float*)d_in[1];
  const float* sinb   = (const float*)d_in[2];
  // d_in[3] = attention_mask (pure causal; implemented analytically)
  const float* q_w  = (const float*)d_in[4];
  const float* k_w  = (const float*)d_in[5];
  const float* v_w  = (const float*)d_in[6];
  const float* o_w  = (const float*)d_in[7];
  const float* q_nw = (const float*)d_in[8];
  const float* k_nw = (const float*)d_in[9];
  float* out = (float*)d_out;

  // d_out (24MB) phase reuse: qkv_proj bf16 [0,16) -> po0 partials [0,6) -> final f32 (fully
  // rewritten by o-gemm). ws phases: hidden_b/qkvw die before q_b/aout overwrite them.
  char* ws = (char*)d_ws;
  const size_t MB = 1u << 20;
  u16*    hidden_b = (u16*)(ws);                        // [0,12)  phase 1
  u16*    qkvw     = (u16*)(ws + 12 * MB);              // [12,18) phase 1
  u16*    q_b      = (u16*)(ws);                        // [0,12)  phase 2+
  u16*    aout     = (u16*)(ws + 12 * MB);              // [12,24) phase 2+
  float2* ml       = (float2*)(ws + 24 * MB);           // [24,24.5)
  u16*    k_b      = (u16*)(ws + 24 * MB + 512 * 1024); // [24.5,26.5)
  u16*    vt_b     = (u16*)(ws + 26 * MB + 512 * 1024); // [26.5,28.5)
  u16*    owb      = (u16*)(ws + 28 * MB + 512 * 1024); // [28.5,33)
  u16*    qkv_proj = (u16*)d_out;                       // bf16 [4096][2048]
  u16*    po0      = (u16*)d_out;                       // attn phase: 6MB partials

  const dim3 blk(256);
  const int M = B_ * T_;  // 4096

  // fp32 -> bf16 converts (weights fused: qkvw rows = [q_w; k_w; v_w])
  {
    const int nh = (B_ * T_ * HID_) / 4;
    const int nq = (H_ * D_ * HID_) / 4;
    const int nk = (HKV_ * D_ * HID_) / 4;
    cvt_f32_bf16<<<2048, blk, 0, stream>>>(hidden, hidden_b, nh);
    cvt_f32_bf16<<<2048, blk, 0, stream>>>(q_w, qkvw, nq);
    cvt_f32_bf16<<<384, blk, 0, stream>>>(k_w, qkvw + (size_t)1536 * HID_, nk);
    cvt_f32_bf16<<<384, blk, 0, stream>>>(v_w, qkvw + (size_t)1792 * HID_, nk);
    cvt_f32_bf16<<<2048, blk, 0, stream>>>(o_w, owb, nq);
  }

  // fused QKV projection: [4096][2048] bf16
  gemm_bt<u16><<<dim3(NQKV_ / 128, M / 128), blk, 0, stream>>>(hidden_b, qkvw, qkv_proj,
                                                               M, NQKV_, HID_);

  norm_rope_cvt<<<16384, blk, 0, stream>>>(qkv_proj, cosb, sinb, q_nw, k_nw,
                                           q_b, k_b, vt_b);

  attn_kernel<<<dim3(B_ * H_, 48), blk, 0, stream>>>(q_b, k_b, vt_b, aout, po0, ml);
  combine_kernel<<<dim3(B_ * H_, 16), blk, 0, stream>>>(aout, po0, ml);

  gemm_bt<float><<<dim3(HID_ / 128, M / 128), blk, 0, stream>>>(aout, owb, out,
                                                                M, HID_, HID_);
}

// Round 4
// 206.475 us; speedup vs baseline: 2.8499x; 1.0464x over previous
//
#include <hip/hip_runtime.h>
#include <hip/hip_bf16.h>

// Qwen3 attention block, bf16-MFMA pipeline, round 4.
// B=2 T=2048 HID=1536 H=12 HKV=2 D=128. All I/O fp32; internal compute bf16.

#define B_   2
#define T_   2048
#define HID_ 1536
#define H_   12
#define HKV_ 2
#define D_   128
#define GQ_  (H_ / HKV_)
#define NQKV_ 2048   // fused projection width: 1536 q + 256 k + 256 v
#define SCALE_ 0.08838834764831845f  // 1/sqrt(128), folded into Q at cast time

typedef unsigned short u16;
typedef __attribute__((ext_vector_type(4))) float f32x4;
typedef __attribute__((ext_vector_type(8))) short bf16x8;
typedef __attribute__((ext_vector_type(4))) unsigned short u16x4;
typedef __attribute__((ext_vector_type(8))) unsigned short u16x8;

__device__ __forceinline__ u16 f2b(float f) {
  union { __hip_bfloat16 h; u16 u; } cv;
  cv.h = __float2bfloat16(f);   // RNE
  return cv.u;
}
__device__ __forceinline__ float b2f(u16 u) {
  union { float f; unsigned i; } cv;
  cv.i = ((unsigned)u) << 16;
  return cv.f;
}

// async global->LDS, 16B per lane; LDS dest = wave-uniform base + lane*16,
// global source address is per-lane (m173 pre-swizzle pattern).
__device__ __forceinline__ void glds16(const u16* g, u16* l) {
  __builtin_amdgcn_global_load_lds((const __attribute__((address_space(1))) void*)g,
                                   (__attribute__((address_space(3))) void*)l, 16, 0, 0);
}

// ---------------- fp32 -> bf16 convert (vectorized, grid-stride) ----------------
__global__ __launch_bounds__(256) void cvt_f32_bf16(const float* __restrict__ src,
                                                    u16* __restrict__ dst, int n4) {
  int i = blockIdx.x * 256 + threadIdx.x;
  const int stride = gridDim.x * 256;
  for (; i < n4; i += stride) {
    const float4 v = reinterpret_cast<const float4*>(src)[i];
    u16x4 o = {f2b(v.x), f2b(v.y), f2b(v.z), f2b(v.w)};
    reinterpret_cast<u16x4*>(dst)[i] = o;
  }
}

// ---------------- bf16 GEMM (m97 structure): C[M][N] = A[M][K] * W[N][K]^T ----------------
__device__ __forceinline__ void cstore(float* p, float v) { *p = v; }
__device__ __forceinline__ void cstore(u16* p, float v) { *p = f2b(v); }

template <typename CT>
__global__ __launch_bounds__(256) void gemm_bt(const u16* __restrict__ A,
                                               const u16* __restrict__ W,
                                               CT* __restrict__ C,
                                               int M, int N, int K) {
  __shared__ __align__(16) u16 As[128 * 32];  // linear: row r at u16 offset r*32
  __shared__ __align__(16) u16 Ws[128 * 32];
  const int tid  = threadIdx.x;
  const int lane = tid & 63;
  const int wid  = tid >> 6;
  const int wr = wid >> 1, wc = wid & 1;
  const int l15 = lane & 15, kg = lane >> 4;
  const int rowBase = blockIdx.y * 128;
  const int colBase = blockIdx.x * 128;

  const int srow = lane >> 2;           // 0..15
  const int scol = (lane & 3) << 3;     // u16 col 0/8/16/24
  const u16* Ab = A + (size_t)(rowBase + wid * 16 + srow) * K + scol;
  const u16* Wb = W + (size_t)(colBase + wid * 16 + srow) * K + scol;
  u16* AsW = &As[wid * 512];
  u16* WsW = &Ws[wid * 512];

  const f32x4 zero4 = {0.f, 0.f, 0.f, 0.f};
  f32x4 acc[4][4];
#pragma unroll
  for (int m = 0; m < 4; ++m)
#pragma unroll
    for (int n = 0; n < 4; ++n) acc[m][n] = zero4;

  for (int k0 = 0; k0 < K; k0 += 32) {
    __syncthreads();  // prev tile's ds_reads done (WAR)
    glds16(Ab + k0, AsW);
    glds16(Ab + (size_t)64 * K + k0, AsW + 2048);
    glds16(Wb + k0, WsW);
    glds16(Wb + (size_t)64 * K + k0, WsW + 2048);
    __syncthreads();  // drains vmcnt: tile ready
    bf16x8 a[4], b[4];
#pragma unroll
    for (int m = 0; m < 4; ++m)
      a[m] = *reinterpret_cast<const bf16x8*>(&As[(wr * 64 + m * 16 + l15) * 32 + kg * 8]);
#pragma unroll
    for (int n = 0; n < 4; ++n)
      b[n] = *reinterpret_cast<const bf16x8*>(&Ws[(wc * 64 + n * 16 + l15) * 32 + kg * 8]);
#pragma unroll
    for (int m = 0; m < 4; ++m)
#pragma unroll
      for (int n = 0; n < 4; ++n)
        acc[m][n] = __builtin_amdgcn_mfma_f32_16x16x32_bf16(a[m], b[n], acc[m][n], 0, 0, 0);
  }
#pragma unroll
  for (int m = 0; m < 4; ++m) {
    const int row0 = rowBase + wr * 64 + m * 16 + kg * 4;
#pragma unroll
    for (int n = 0; n < 4; ++n) {
      const int col = colBase + wc * 64 + n * 16 + l15;
#pragma unroll
      for (int r = 0; r < 4; ++r) cstore(&C[(size_t)(row0 + r) * N + col], acc[m][n][r]);
    }
  }
}

// ---------------- RMSNorm + RoPE + cast (reads fused bf16 qkv_proj) ----------------
// v path writes vt_b [b][hkv][d][t'] with t' kappa^-1-permuted within each 64-token
// tile so the attn PV A-fragment needs zero cross-lane P redistribution.
__global__ __launch_bounds__(256) void norm_rope_cvt(
    const u16* __restrict__ qkv, const float* __restrict__ cosb,
    const float* __restrict__ sinb, const float* __restrict__ q_nw,
    const float* __restrict__ k_nw, u16* __restrict__ q_b,
    u16* __restrict__ k_b, u16* __restrict__ vt_b) {
  const int gwave = (int)((blockIdx.x * 256 + threadIdx.x) >> 6);
  const int lane = threadIdx.x & 63;
  const int NQ = B_ * T_ * H_;    // 49152
  const int NK = B_ * T_ * HKV_;  // 8192
  if (gwave < NQ) {
    const int bt = gwave / H_, h = gwave - bt * H_;
    const u16* src = qkv + (size_t)bt * NQKV_ + h * D_;
    const float x1 = b2f(src[lane]), x2 = b2f(src[lane + 64]);
    float ss = x1 * x1 + x2 * x2;
#pragma unroll
    for (int m = 32; m >= 1; m >>= 1) ss += __shfl_xor(ss, m);
    const float rinv = rsqrtf(ss * (1.0f / D_) + 1e-6f);
    const float c1 = cosb[(size_t)bt * D_ + lane], c2 = cosb[(size_t)bt * D_ + lane + 64];
    const float s1 = sinb[(size_t)bt * D_ + lane], s2 = sinb[(size_t)bt * D_ + lane + 64];
    const float n1 = x1 * rinv * q_nw[lane], n2 = x2 * rinv * q_nw[lane + 64];
    const float o1 = (n1 * c1 - n2 * s1) * SCALE_;
    const float o2 = (n2 * c2 + n1 * s2) * SCALE_;
    const int b = bt >> 11, t = bt & (T_ - 1);
    u16* dst = q_b + ((size_t)(b * H_ + h) * T_ + t) * D_;
    dst[lane] = f2b(o1);
    dst[lane + 64] = f2b(o2);
  } else if (gwave < NQ + NK) {
    const int r = gwave - NQ;
    const int bt = r >> 1, hv = r & 1;
    const u16* src = qkv + (size_t)bt * NQKV_ + 1536 + hv * D_;
    const float x1 = b2f(src[lane]), x2 = b2f(src[lane + 64]);
    float ss = x1 * x1 + x2 * x2;
#pragma unroll
    for (int m = 32; m >= 1; m >>= 1) ss += __shfl_xor(ss, m);
    const float rinv = rsqrtf(ss * (1.0f / D_) + 1e-6f);
    const float c1 = cosb[(size_t)bt * D_ + lane], c2 = cosb[(size_t)bt * D_ + lane + 64];
    const float s1 = sinb[(size_t)bt * D_ + lane], s2 = sinb[(size_t)bt * D_ + lane + 64];
    const float n1 = x1 * rinv * k_nw[lane], n2 = x2 * rinv * k_nw[lane + 64];
    const float o1 = n1 * c1 - n2 * s1;
    const float o2 = n2 * c2 + n1 * s2;
    const int b = bt >> 11, t = bt & (T_ - 1);
    u16* dst = k_b + ((size_t)(b * HKV_ + hv) * T_ + t) * D_;
    dst[lane] = f2b(o1);
    dst[lane + 64] = f2b(o2);
  } else {
    const int r = gwave - NQ - NK;
    const int bt = r >> 1, hv = r & 1;
    const u16* src = qkv + (size_t)bt * NQKV_ + 1792 + hv * D_;
    const float x1 = b2f(src[lane]), x2 = b2f(src[lane + 64]);
    const int b = bt >> 11, t = bt & (T_ - 1);
    // kappa^-1: t' within 64-tile = (k&32)|(((k>>2)&3)<<3)|(((k>>4)&1)<<2)|(k&3)
    const int kk = t & 63;
    const int tp = (t & ~63) | (kk & 32) | (((kk >> 2) & 3) << 3) |
                   (((kk >> 4) & 1) << 2) | (kk & 3);
    u16* dst = vt_b + (size_t)(b * HKV_ + hv) * D_ * T_;
    dst[(size_t)lane * T_ + tp] = f2b(x1);
    dst[(size_t)(lane + 64) * T_ + tp] = f2b(x2);
  }
}

// ---------------- Flash attention, causal, GQA, split-K, swapped-QK ----------------
// Block = 4 waves x 32 q-rows = 128 q-rows. blockIdx.y in [0,24): y<16 -> (qt=y,s=0)
// covering kt 0..min(2qt+1,15); y>=16 -> (qt=y-8, s=1) covering kt 16..2qt+1.
// K LDS [64 k][128 d], V LDS [128 d][64 k'] (k' kappa-permuted in vt_b), both
// XOR-bank-swizzled (source-preswizzled for global_load_lds, swizzled reads).
// Swapped QK^T: mfma(A=K,B=Q) -> lane l15 owns q-row; softmax fully in-lane.
__global__ __launch_bounds__(256) void attn_kernel(const u16* __restrict__ q_b,
                                                   const u16* __restrict__ k_b,
                                                   const u16* __restrict__ vt_b,
                                                   u16* __restrict__ aout,
                                                   u16* __restrict__ po0,
                                                   float2* __restrict__ ml) {
  __shared__ __align__(16) u16 Ks[2][64 * 128];
  __shared__ __align__(16) u16 Vs[2][128 * 64];
  const int bh = blockIdx.x;  // 0..23
  const int y = blockIdx.y;   // 0..23
  const int qt = (y < 16) ? y : (y - 8);
  const int s = (y < 16) ? 0 : 1;
  const int kt0 = s * 16;
  const int ktend = (s == 0) ? min(2 * qt + 1, 15) : (2 * qt + 1);
  const bool splitq = (qt >= 8);
  const int b = bh / H_, h = bh - b * H_;
  const int kvh = h / GQ_;
  const int tid = threadIdx.x;
  const int w = tid >> 6, lane = tid & 63;
  const int l15 = lane & 15, kg = lane >> 4;
  const int qbase = qt * 128;

  const u16* Kb = k_b + (size_t)(b * HKV_ + kvh) * T_ * D_;
  const u16* Vb = vt_b + (size_t)(b * HKV_ + kvh) * D_ * T_;

  // Q fragments (B-operand): qf[qb][s4], 32 q-rows per wave
  bf16x8 qf[2][4];
#pragma unroll
  for (int qb = 0; qb < 2; ++qb) {
    const u16* qrow =
        q_b + ((size_t)(b * H_ + h) * T_ + qbase + w * 32 + qb * 16 + l15) * D_;
#pragma unroll
    for (int s4 = 0; s4 < 4; ++s4)
      qf[qb][s4] = *reinterpret_cast<const bf16x8*>(qrow + s4 * 32 + kg * 8);
  }

  // per-lane staging source offsets (4 chunks of 1KB each for K and V)
  int kK[4], vK[4];
#pragma unroll
  for (int c = 0; c < 4; ++c) {
    const int ch = w * 4 + c;
    const int kr = ch * 4 + (lane >> 4);            // K LDS row
    kK[c] = kr * D_ + (((lane & 15) << 3) ^ ((kr & 7) << 3));
    const int dr = ch * 8 + (lane >> 3);            // V LDS row (d)
    vK[c] = dr * T_ + (((lane & 7) << 3) ^ ((dr & 7) << 3));
  }

  // fragment read offsets (u16 units), XOR bank-swizzled
  // kf(n,s4): (n*16+l15)*128 + ((s4*32+kg*8) ^ ((l15&7)<<3))
  // vf(n,ks): (n*16+l15)*64  + ((ks*32+kg*8) ^ ((l15&7)<<3))
  const int xorv = (l15 & 7) << 3;

  const f32x4 zero4 = {0.f, 0.f, 0.f, 0.f};
  f32x4 o[2][8];
#pragma unroll
  for (int qb = 0; qb < 2; ++qb)
#pragma unroll
    for (int n = 0; n < 8; ++n) o[qb][n] = zero4;
  float m[2] = {0.f, 0.f};       // init 0: masked tiles give p=exp(-3e38)=0 safely
  float lsum[2] = {0.f, 0.f};

  // prologue: stage first tile into buf 0
  {
    const size_t kb = (size_t)kt0 * 64;
#pragma unroll
    for (int c = 0; c < 4; ++c) {
      glds16(Kb + kb * D_ + kK[c], &Ks[0][(w * 4 + c) * 512]);
      glds16(Vb + kb + vK[c], &Vs[0][(w * 4 + c) * 512]);
    }
  }
  __syncthreads();  // vmcnt(0) drain + barrier: buf0 ready
  int cur = 0;

  for (int kt = kt0; kt <= ktend; ++kt) {
    if (kt < ktend) {  // stage next tile into other buffer; overlaps compute
      const size_t kb = (size_t)(kt + 1) * 64;
#pragma unroll
      for (int c = 0; c < 4; ++c) {
        glds16(Kb + kb * D_ + kK[c], &Ks[cur ^ 1][(w * 4 + c) * 512]);
        glds16(Vb + kb + vK[c], &Vs[cur ^ 1][(w * 4 + c) * 512]);
      }
    }
    // QK^T (swapped): sc[qb][n] = S^T, lane: q=l15, k=n*16+kg*4+r
    f32x4 sc[2][4];
#pragma unroll
    for (int qb = 0; qb < 2; ++qb)
#pragma unroll
      for (int n = 0; n < 4; ++n) sc[qb][n] = zero4;
#pragma unroll
    for (int n = 0; n < 4; ++n)
#pragma unroll
      for (int s4 = 0; s4 < 4; ++s4) {
        const int koff = (n * 16 + l15) * 128 + ((s4 * 32 + kg * 8) ^ xorv);
        bf16x8 kf = *reinterpret_cast<const bf16x8*>(&Ks[cur][koff]);
#pragma unroll
        for (int qb = 0; qb < 2; ++qb)
          sc[qb][n] = __builtin_amdgcn_mfma_f32_16x16x32_bf16(kf, qf[qb][s4],
                                                              sc[qb][n], 0, 0, 0);
      }
    if (kt >= 2 * qt) {  // diagonal region: mask k > q
#pragma unroll
      for (int qb = 0; qb < 2; ++qb) {
        const int qg = w * 32 + qb * 16 + l15;           // q within block
        const int kbb = (kt - 2 * qt) * 64;              // k-tile base within block
#pragma unroll
        for (int n = 0; n < 4; ++n)
#pragma unroll
          for (int r = 0; r < 4; ++r)
            if (kbb + n * 16 + kg * 4 + r > qg) sc[qb][n][r] = -3e38f;
      }
    }
    // in-lane softmax (q = l15), defer-max (T13)
    float pm[2];
#pragma unroll
    for (int qb = 0; qb < 2; ++qb) {
      float v = sc[qb][0][0];
#pragma unroll
      for (int n = 0; n < 4; ++n)
#pragma unroll
        for (int r = 0; r < 4; ++r) v = fmaxf(v, sc[qb][n][r]);
      v = fmaxf(v, __shfl_xor(v, 16));
      v = fmaxf(v, __shfl_xor(v, 32));
      pm[qb] = v;
    }
    if (__any((pm[0] > m[0] + 8.f) | (pm[1] > m[1] + 8.f))) {
#pragma unroll
      for (int qb = 0; qb < 2; ++qb) {
        const float mn = fmaxf(m[qb], pm[qb]);
        const float al = __expf(m[qb] - mn);
        m[qb] = mn;
        lsum[qb] *= al;
        float alT[4];
#pragma unroll
        for (int r = 0; r < 4; ++r)
          alT[r] = __shfl(al, (lane & 48) | (kg * 4 + r));
#pragma unroll
        for (int n = 0; n < 8; ++n)
#pragma unroll
          for (int r = 0; r < 4; ++r) o[qb][n][r] *= alT[r];
      }
    }
#pragma unroll
    for (int qb = 0; qb < 2; ++qb) {
      float rs = 0.f;
#pragma unroll
      for (int n = 0; n < 4; ++n)
#pragma unroll
        for (int r = 0; r < 4; ++r) {
          const float p = __expf(sc[qb][n][r] - m[qb]);
          sc[qb][n][r] = p;
          rs += p;
        }
      rs += __shfl_xor(rs, 16);
      rs += __shfl_xor(rs, 32);
      lsum[qb] += rs;
    }
    // pack P -> A-fragments (pure in-lane thanks to kappa-permuted V)
    bf16x8 pf[2][2];
#pragma unroll
    for (int qb = 0; qb < 2; ++qb)
#pragma unroll
      for (int ks = 0; ks < 2; ++ks)
#pragma unroll
        for (int r = 0; r < 4; ++r) {
          pf[qb][ks][r] = (short)f2b(sc[qb][2 * ks][r]);
          pf[qb][ks][r + 4] = (short)f2b(sc[qb][2 * ks + 1][r]);
        }
    // PV: o[qb][n] += pf[qb][ks] x vf(n,ks)
#pragma unroll
    for (int n = 0; n < 8; ++n)
#pragma unroll
      for (int ks = 0; ks < 2; ++ks) {
        const int voff = (n * 16 + l15) * 64 + ((ks * 32 + kg * 8) ^ xorv);
        bf16x8 vf = *reinterpret_cast<const bf16x8*>(&Vs[cur][voff]);
#pragma unroll
        for (int qb = 0; qb < 2; ++qb)
          o[qb][n] = __builtin_amdgcn_mfma_f32_16x16x32_bf16(pf[qb][ks], vf,
                                                             o[qb][n], 0, 0, 0);
      }
    if (kt < ktend) {
      __syncthreads();  // vmcnt(0): next buf staged (all waves) + prev consumed
      cur ^= 1;
    }
  }

  // epilogue: o[qb][n][r] is O[q = qb*16+kg*4+r][d = n*16+l15]
  if (!splitq) {
    float invT[2][4];
#pragma unroll
    for (int qb = 0; qb < 2; ++qb) {
      const float inv = 1.0f / lsum[qb];
#pragma unroll
      for (int r = 0; r < 4; ++r)
        invT[qb][r] = __shfl(inv, (lane & 48) | (kg * 4 + r));
    }
#pragma unroll
    for (int qb = 0; qb < 2; ++qb) {
      const int t0 = qbase + w * 32 + qb * 16 + kg * 4;
#pragma unroll
      for (int n = 0; n < 8; ++n)
#pragma unroll
        for (int r = 0; r < 4; ++r)
          aout[(size_t)(b * T_ + t0 + r) * (H_ * D_) + h * D_ + n * 16 + l15] =
              f2b(o[qb][n][r] * invT[qb][r]);
    }
  } else {
    const int slot = bh * 8 + (qt - 8);
    if (kg == 0) {
#pragma unroll
      for (int qb = 0; qb < 2; ++qb) {
        float2 v;
        v.x = m[qb];
        v.y = lsum[qb];
        ml[(size_t)(slot * 2 + s) * 128 + w * 32 + qb * 16 + l15] = v;
      }
    }
    if (s == 1) {  // unnormalized partial into this q-tile's aout slot
#pragma unroll
      for (int qb = 0; qb < 2; ++qb) {
        const int t0 = qbase + w * 32 + qb * 16 + kg * 4;
#pragma unroll
        for (int n = 0; n < 8; ++n)
#pragma unroll
          for (int r = 0; r < 4; ++r)
            aout[(size_t)(b * T_ + t0 + r) * (H_ * D_) + h * D_ + n * 16 + l15] =
                f2b(o[qb][n][r]);
      }
    } else {       // unnormalized partial into scratch
#pragma unroll
      for (int qb = 0; qb < 2; ++qb) {
        const int row0 = w * 32 + qb * 16 + kg * 4;
#pragma unroll
        for (int n = 0; n < 8; ++n)
#pragma unroll
          for (int r = 0; r < 4; ++r)
            po0[((size_t)slot * 128 + row0 + r) * 128 + n * 16 + l15] =
                f2b(o[qb][n][r]);
      }
    }
  }
}

// ---------------- combine split-K partials (128-row q-tiles) ----------------
__global__ __launch_bounds__(256) void combine_kernel(u16* __restrict__ aout,
                                                      const u16* __restrict__ po0,
                                                      const float2* __restrict__ ml) {
  const int bh = blockIdx.x;        // 0..23
  const int qt8 = blockIdx.y;       // 0..7 -> qt = 8+qt8
  const int slot = bh * 8 + qt8;
  const int b = bh / H_, h = bh - b * H_;
  const int t0 = (qt8 + 8) * 128;
  const int tid = threadIdx.x;
  const int row = tid >> 1;
  const int colc = (tid & 1) << 6;  // 64-elem column chunk

  const float2 ml0 = ml[(size_t)(slot * 2 + 0) * 128 + row];
  const float2 ml1 = ml[(size_t)(slot * 2 + 1) * 128 + row];
  const float mm = fmaxf(ml0.x, ml1.x);
  const float c0 = __expf(ml0.x - mm), c1 = __expf(ml1.x - mm);
  const float inv = 1.0f / (ml0.y * c0 + ml1.y * c1);
  const float s0 = c0 * inv, s1 = c1 * inv;

  const u16* p0 = po0 + ((size_t)slot * 128 + row) * 128 + colc;
  u16* a = aout + (size_t)(b * T_ + t0 + row) * (H_ * D_) + h * D_ + colc;
#pragma unroll
  for (int j = 0; j < 8; ++j) {
    u16x8 v0 = *reinterpret_cast<const u16x8*>(p0 + j * 8);
    u16x8 v1 = *reinterpret_cast<const u16x8*>(a + j * 8);
    u16x8 outv;
#pragma unroll
    for (int e = 0; e < 8; ++e) outv[e] = f2b(b2f(v0[e]) * s0 + b2f(v1[e]) * s1);
    *reinterpret_cast<u16x8*>(a + j * 8) = outv;
  }
}

extern "C" void kernel_launch(void* const* d_in, const int* in_sizes, int n_in,
                              void* d_out, int out_size, void* d_ws, size_t ws_size,
                              hipStream_t stream) {
  const float* hidden = (const float*)d_in[0];
  const float* cosb   = (const float*)d_in[1];
  const float* sinb   = (const float*)d_in[2];
  // d_in[3] = attention_mask (pure causal; implemented analytically)
  const float* q_w  = (const float*)d_in[4];
  const float* k_w  = (const float*)d_in[5];
  const float* v_w  = (const float*)d_in[6];
  const float* o_w  = (const float*)d_in[7];
  const float* q_nw = (const float*)d_in[8];
  const float* k_nw = (const float*)d_in[9];
  float* out = (float*)d_out;

  // d_out (24MB) phase reuse: qkv_proj bf16 [0,16) -> po0 partials [0,6) -> final f32
  // (fully rewritten by o-gemm). ws: hidden_b/qkvw die before q_b/aout overwrite.
  char* ws = (char*)d_ws;
  const size_t MB = 1u << 20;
  u16*    hidden_b = (u16*)(ws);                        // [0,12)  phase 1
  u16*    qkvw     = (u16*)(ws + 12 * MB);              // [12,18) phase 1
  u16*    q_b      = (u16*)(ws);                        // [0,12)  phase 2+
  u16*    aout     = (u16*)(ws + 12 * MB);              // [12,24) phase 2+
  float2* ml       = (float2*)(ws + 24 * MB);           // [24,24.4)
  u16*    k_b      = (u16*)(ws + 24 * MB + 512 * 1024); // [24.5,26.5)
  u16*    vt_b     = (u16*)(ws + 26 * MB + 512 * 1024); // [26.5,28.5)
  u16*    owb      = (u16*)(ws + 28 * MB + 512 * 1024); // [28.5,33)
  u16*    qkv_proj = (u16*)d_out;                       // bf16 [4096][2048]
  u16*    po0      = (u16*)d_out;                       // attn phase: 6MB partials

  const dim3 blk(256);
  const int M = B_ * T_;  // 4096

  // fp32 -> bf16 converts (weights fused: qkvw rows = [q_w; k_w; v_w])
  {
    const int nh = (B_ * T_ * HID_) / 4;
    const int nq = (H_ * D_ * HID_) / 4;
    const int nk = (HKV_ * D_ * HID_) / 4;
    cvt_f32_bf16<<<2048, blk, 0, stream>>>(hidden, hidden_b, nh);
    cvt_f32_bf16<<<2048, blk, 0, stream>>>(q_w, qkvw, nq);
    cvt_f32_bf16<<<384, blk, 0, stream>>>(k_w, qkvw + (size_t)1536 * HID_, nk);
    cvt_f32_bf16<<<384, blk, 0, stream>>>(v_w, qkvw + (size_t)1792 * HID_, nk);
    cvt_f32_bf16<<<2048, blk, 0, stream>>>(o_w, owb, nq);
  }

  // fused QKV projection: [4096][2048] bf16
  gemm_bt<u16><<<dim3(NQKV_ / 128, M / 128), blk, 0, stream>>>(hidden_b, qkvw, qkv_proj,
                                                               M, NQKV_, HID_);

  norm_rope_cvt<<<16384, blk, 0, stream>>>(qkv_proj, cosb, sinb, q_nw, k_nw,
                                           q_b, k_b, vt_b);

  attn_kernel<<<dim3(B_ * H_, 24), blk, 0, stream>>>(q_b, k_b, vt_b, aout, po0, ml);
  combine_kernel<<<dim3(B_ * H_, 8), blk, 0, stream>>>(aout, po0, ml);

  gemm_bt<float><<<dim3(HID_ / 128, M / 128), blk, 0, stream>>>(aout, owb, out,
                                                                M, HID_, HID_);
}

// Round 5
// 197.377 us; speedup vs baseline: 2.9813x; 1.0461x over previous
//
#include <hip/hip_runtime.h>
#include <hip/hip_bf16.h>

// Qwen3 attention block, bf16-MFMA pipeline, round 5.
// B=2 T=2048 HID=1536 H=12 HKV=2 D=128. All I/O fp32; internal compute bf16.

#define B_   2
#define T_   2048
#define HID_ 1536
#define H_   12
#define HKV_ 2
#define D_   128
#define GQ_  (H_ / HKV_)
#define NQKV_ 2048   // fused projection width: 1536 q + 256 k + 256 v
#define SCALE_ 0.08838834764831845f  // 1/sqrt(128), folded into Q at cast time

typedef unsigned short u16;
typedef __attribute__((ext_vector_type(4))) float f32x4;
typedef __attribute__((ext_vector_type(8))) short bf16x8;
typedef __attribute__((ext_vector_type(4))) unsigned short u16x4;
typedef __attribute__((ext_vector_type(8))) unsigned short u16x8;

__device__ __forceinline__ u16 f2b(float f) {
  union { __hip_bfloat16 h; u16 u; } cv;
  cv.h = __float2bfloat16(f);   // RNE
  return cv.u;
}
__device__ __forceinline__ float b2f(u16 u) {
  union { float f; unsigned i; } cv;
  cv.i = ((unsigned)u) << 16;
  return cv.f;
}

// async global->LDS, 16B per lane; LDS dest = wave-uniform base + lane*16,
// global source address is per-lane (m173 pre-swizzle pattern).
__device__ __forceinline__ void glds16(const u16* g, u16* l) {
  __builtin_amdgcn_global_load_lds((const __attribute__((address_space(1))) void*)g,
                                   (__attribute__((address_space(3))) void*)l, 16, 0, 0);
}

// ---------------- fp32 -> bf16 convert (vectorized, grid-stride) ----------------
__global__ __launch_bounds__(256) void cvt_f32_bf16(const float* __restrict__ src,
                                                    u16* __restrict__ dst, int n4) {
  int i = blockIdx.x * 256 + threadIdx.x;
  const int stride = gridDim.x * 256;
  for (; i < n4; i += stride) {
    const float4 v = reinterpret_cast<const float4*>(src)[i];
    u16x4 o = {f2b(v.x), f2b(v.y), f2b(v.z), f2b(v.w)};
    reinterpret_cast<u16x4*>(dst)[i] = o;
  }
}

// ---------------- bf16 GEMM (m97 structure): C[M][N] = A[M][K] * W[N][K]^T ----------------
__device__ __forceinline__ void cstore(float* p, float v) { *p = v; }
__device__ __forceinline__ void cstore(u16* p, float v) { *p = f2b(v); }

template <typename CT>
__global__ __launch_bounds__(256) void gemm_bt(const u16* __restrict__ A,
                                               const u16* __restrict__ W,
                                               CT* __restrict__ C,
                                               int M, int N, int K) {
  __shared__ __align__(16) u16 As[128 * 32];  // linear: row r at u16 offset r*32
  __shared__ __align__(16) u16 Ws[128 * 32];
  const int tid  = threadIdx.x;
  const int lane = tid & 63;
  const int wid  = tid >> 6;
  const int wr = wid >> 1, wc = wid & 1;
  const int l15 = lane & 15, kg = lane >> 4;
  const int rowBase = blockIdx.y * 128;
  const int colBase = blockIdx.x * 128;

  const int srow = lane >> 2;           // 0..15
  const int scol = (lane & 3) << 3;     // u16 col 0/8/16/24
  const u16* Ab = A + (size_t)(rowBase + wid * 16 + srow) * K + scol;
  const u16* Wb = W + (size_t)(colBase + wid * 16 + srow) * K + scol;
  u16* AsW = &As[wid * 512];
  u16* WsW = &Ws[wid * 512];

  const f32x4 zero4 = {0.f, 0.f, 0.f, 0.f};
  f32x4 acc[4][4];
#pragma unroll
  for (int m = 0; m < 4; ++m)
#pragma unroll
    for (int n = 0; n < 4; ++n) acc[m][n] = zero4;

  for (int k0 = 0; k0 < K; k0 += 32) {
    __syncthreads();  // prev tile's ds_reads done (WAR)
    glds16(Ab + k0, AsW);
    glds16(Ab + (size_t)64 * K + k0, AsW + 2048);
    glds16(Wb + k0, WsW);
    glds16(Wb + (size_t)64 * K + k0, WsW + 2048);
    __syncthreads();  // drains vmcnt: tile ready
    bf16x8 a[4], b[4];
#pragma unroll
    for (int m = 0; m < 4; ++m)
      a[m] = *reinterpret_cast<const bf16x8*>(&As[(wr * 64 + m * 16 + l15) * 32 + kg * 8]);
#pragma unroll
    for (int n = 0; n < 4; ++n)
      b[n] = *reinterpret_cast<const bf16x8*>(&Ws[(wc * 64 + n * 16 + l15) * 32 + kg * 8]);
#pragma unroll
    for (int m = 0; m < 4; ++m)
#pragma unroll
      for (int n = 0; n < 4; ++n)
        acc[m][n] = __builtin_amdgcn_mfma_f32_16x16x32_bf16(a[m], b[n], acc[m][n], 0, 0, 0);
  }
#pragma unroll
  for (int m = 0; m < 4; ++m) {
    const int row0 = rowBase + wr * 64 + m * 16 + kg * 4;
#pragma unroll
    for (int n = 0; n < 4; ++n) {
      const int col = colBase + wc * 64 + n * 16 + l15;
#pragma unroll
      for (int r = 0; r < 4; ++r) cstore(&C[(size_t)(row0 + r) * N + col], acc[m][n][r]);
    }
  }
}

// ---------------- RMSNorm + RoPE + cast (reads fused bf16 qkv_proj) ----------------
// v path writes vt_b [b][hkv][d][t'] with t' kappa^-1-permuted within each 64-token
// tile so the attn PV A-fragment needs zero cross-lane P redistribution.
__global__ __launch_bounds__(256) void norm_rope_cvt(
    const u16* __restrict__ qkv, const float* __restrict__ cosb,
    const float* __restrict__ sinb, const float* __restrict__ q_nw,
    const float* __restrict__ k_nw, u16* __restrict__ q_b,
    u16* __restrict__ k_b, u16* __restrict__ vt_b) {
  const int gwave = (int)((blockIdx.x * 256 + threadIdx.x) >> 6);
  const int lane = threadIdx.x & 63;
  const int NQ = B_ * T_ * H_;    // 49152
  const int NK = B_ * T_ * HKV_;  // 8192
  if (gwave < NQ) {
    const int bt = gwave / H_, h = gwave - bt * H_;
    const u16* src = qkv + (size_t)bt * NQKV_ + h * D_;
    const float x1 = b2f(src[lane]), x2 = b2f(src[lane + 64]);
    float ss = x1 * x1 + x2 * x2;
#pragma unroll
    for (int m = 32; m >= 1; m >>= 1) ss += __shfl_xor(ss, m);
    const float rinv = rsqrtf(ss * (1.0f / D_) + 1e-6f);
    const float c1 = cosb[(size_t)bt * D_ + lane], c2 = cosb[(size_t)bt * D_ + lane + 64];
    const float s1 = sinb[(size_t)bt * D_ + lane], s2 = sinb[(size_t)bt * D_ + lane + 64];
    const float n1 = x1 * rinv * q_nw[lane], n2 = x2 * rinv * q_nw[lane + 64];
    const float o1 = (n1 * c1 - n2 * s1) * SCALE_;
    const float o2 = (n2 * c2 + n1 * s2) * SCALE_;
    const int b = bt >> 11, t = bt & (T_ - 1);
    u16* dst = q_b + ((size_t)(b * H_ + h) * T_ + t) * D_;
    dst[lane] = f2b(o1);
    dst[lane + 64] = f2b(o2);
  } else if (gwave < NQ + NK) {
    const int r = gwave - NQ;
    const int bt = r >> 1, hv = r & 1;
    const u16* src = qkv + (size_t)bt * NQKV_ + 1536 + hv * D_;
    const float x1 = b2f(src[lane]), x2 = b2f(src[lane + 64]);
    float ss = x1 * x1 + x2 * x2;
#pragma unroll
    for (int m = 32; m >= 1; m >>= 1) ss += __shfl_xor(ss, m);
    const float rinv = rsqrtf(ss * (1.0f / D_) + 1e-6f);
    const float c1 = cosb[(size_t)bt * D_ + lane], c2 = cosb[(size_t)bt * D_ + lane + 64];
    const float s1 = sinb[(size_t)bt * D_ + lane], s2 = sinb[(size_t)bt * D_ + lane + 64];
    const float n1 = x1 * rinv * k_nw[lane], n2 = x2 * rinv * k_nw[lane + 64];
    const float o1 = n1 * c1 - n2 * s1;
    const float o2 = n2 * c2 + n1 * s2;
    const int b = bt >> 11, t = bt & (T_ - 1);
    u16* dst = k_b + ((size_t)(b * HKV_ + hv) * T_ + t) * D_;
    dst[lane] = f2b(o1);
    dst[lane + 64] = f2b(o2);
  } else {
    const int r = gwave - NQ - NK;
    const int bt = r >> 1, hv = r & 1;
    const u16* src = qkv + (size_t)bt * NQKV_ + 1792 + hv * D_;
    const float x1 = b2f(src[lane]), x2 = b2f(src[lane + 64]);
    const int b = bt >> 11, t = bt & (T_ - 1);
    // kappa^-1: t' within 64-tile = (k&32)|(((k>>2)&3)<<3)|(((k>>4)&1)<<2)|(k&3)
    const int kk = t & 63;
    const int tp = (t & ~63) | (kk & 32) | (((kk >> 2) & 3) << 3) |
                   (((kk >> 4) & 1) << 2) | (kk & 3);
    u16* dst = vt_b + (size_t)(b * HKV_ + hv) * D_ * T_;
    dst[(size_t)lane * T_ + tp] = f2b(x1);
    dst[(size_t)(lane + 64) * T_ + tp] = f2b(x2);
  }
}

// ---------------- Flash attention, causal, GQA, equal-split-K, swapped-QK ----------------
// Block = 4 waves x 32 q-rows = 128 q-rows, SINGLE-buffered 32KB LDS (3 blocks/CU
// co-resident provide cross-block overlap; all 576 blocks resident at launch).
// Work item map (y interleaves big/small for per-CU balance):
//   item<8:  qt=item, full range kt 0..2qt+1
//   8..15:   qt=item, s=0 half: kt 0..qt         (partial -> po0 + ml)
//   16..23:  qt=item-8, s=1 half: kt qt+1..2qt+1 (partial -> aout + ml)
// Swapped QK^T: mfma(A=K,B=Q) -> lane l15 owns q-row; softmax fully in-lane.
__global__ __launch_bounds__(256) void attn_kernel(const u16* __restrict__ q_b,
                                                   const u16* __restrict__ k_b,
                                                   const u16* __restrict__ vt_b,
                                                   u16* __restrict__ aout,
                                                   u16* __restrict__ po0,
                                                   float2* __restrict__ ml) {
  __shared__ __align__(16) u16 Ks[64 * 128];
  __shared__ __align__(16) u16 Vs[128 * 64];
  const int bh = blockIdx.x;  // 0..23
  const int y = blockIdx.y;   // 0..23
  const int item = (y & 1) ? (23 - (y >> 1)) : (y >> 1);
  int qt, s, kt0, ktend;
  bool splitq;
  if (item < 8) {
    qt = item; s = 0; kt0 = 0; ktend = 2 * qt + 1; splitq = false;
  } else if (item < 16) {
    qt = item; s = 0; kt0 = 0; ktend = qt; splitq = true;
  } else {
    qt = item - 8; s = 1; kt0 = qt + 1; ktend = 2 * qt + 1; splitq = true;
  }
  const int b = bh / H_, h = bh - b * H_;
  const int kvh = h / GQ_;
  const int tid = threadIdx.x;
  const int w = tid >> 6, lane = tid & 63;
  const int l15 = lane & 15, kg = lane >> 4;
  const int qbase = qt * 128;

  const u16* Kb = k_b + (size_t)(b * HKV_ + kvh) * T_ * D_;
  const u16* Vb = vt_b + (size_t)(b * HKV_ + kvh) * D_ * T_;

  // Q fragments (B-operand): qf[qb][s4], 32 q-rows per wave
  bf16x8 qf[2][4];
#pragma unroll
  for (int qb = 0; qb < 2; ++qb) {
    const u16* qrow =
        q_b + ((size_t)(b * H_ + h) * T_ + qbase + w * 32 + qb * 16 + l15) * D_;
#pragma unroll
    for (int s4 = 0; s4 < 4; ++s4)
      qf[qb][s4] = *reinterpret_cast<const bf16x8*>(qrow + s4 * 32 + kg * 8);
  }

  // per-lane staging source offsets (4 chunks of 1KB each for K and V)
  int kK[4], vK[4];
#pragma unroll
  for (int c = 0; c < 4; ++c) {
    const int ch = w * 4 + c;
    const int kr = ch * 4 + (lane >> 4);            // K LDS row
    kK[c] = kr * D_ + (((lane & 15) << 3) ^ ((kr & 7) << 3));
    const int dr = ch * 8 + (lane >> 3);            // V LDS row (d)
    vK[c] = dr * T_ + (((lane & 7) << 3) ^ ((dr & 7) << 3));
  }

  // fragment read offsets (u16 units), XOR bank-swizzled
  const int xorv = (l15 & 7) << 3;

  const f32x4 zero4 = {0.f, 0.f, 0.f, 0.f};
  f32x4 o[2][8];
#pragma unroll
  for (int qb = 0; qb < 2; ++qb)
#pragma unroll
    for (int n = 0; n < 8; ++n) o[qb][n] = zero4;
  float m[2] = {0.f, 0.f};       // init 0: masked tiles give p=exp(-3e38)=0 safely
  float lsum[2] = {0.f, 0.f};

  for (int kt = kt0; kt <= ktend; ++kt) {
    __syncthreads();  // previous tile fully consumed (WAR)
    {
      const size_t kb = (size_t)kt * 64;
#pragma unroll
      for (int c = 0; c < 4; ++c) {
        glds16(Kb + kb * D_ + kK[c], &Ks[(w * 4 + c) * 512]);
        glds16(Vb + kb + vK[c], &Vs[(w * 4 + c) * 512]);
      }
    }
    __syncthreads();  // vmcnt(0) drain: tile ready
    // QK^T (swapped): sc[qb][n] = S^T, lane: q=l15, k=n*16+kg*4+r
    f32x4 sc[2][4];
#pragma unroll
    for (int qb = 0; qb < 2; ++qb)
#pragma unroll
      for (int n = 0; n < 4; ++n) sc[qb][n] = zero4;
#pragma unroll
    for (int n = 0; n < 4; ++n)
#pragma unroll
      for (int s4 = 0; s4 < 4; ++s4) {
        const int koff = (n * 16 + l15) * 128 + ((s4 * 32 + kg * 8) ^ xorv);
        bf16x8 kf = *reinterpret_cast<const bf16x8*>(&Ks[koff]);
#pragma unroll
        for (int qb = 0; qb < 2; ++qb)
          sc[qb][n] = __builtin_amdgcn_mfma_f32_16x16x32_bf16(kf, qf[qb][s4],
                                                              sc[qb][n], 0, 0, 0);
      }
    if (kt >= 2 * qt) {  // diagonal region: mask k > q
#pragma unroll
      for (int qb = 0; qb < 2; ++qb) {
        const int qg = w * 32 + qb * 16 + l15;           // q within block
        const int kbb = (kt - 2 * qt) * 64;              // k-tile base within block
#pragma unroll
        for (int n = 0; n < 4; ++n)
#pragma unroll
          for (int r = 0; r < 4; ++r)
            if (kbb + n * 16 + kg * 4 + r > qg) sc[qb][n][r] = -3e38f;
      }
    }
    // in-lane softmax (q = l15), defer-max (T13)
    float pm[2];
#pragma unroll
    for (int qb = 0; qb < 2; ++qb) {
      float v = sc[qb][0][0];
#pragma unroll
      for (int n = 0; n < 4; ++n)
#pragma unroll
        for (int r = 0; r < 4; ++r) v = fmaxf(v, sc[qb][n][r]);
      v = fmaxf(v, __shfl_xor(v, 16));
      v = fmaxf(v, __shfl_xor(v, 32));
      pm[qb] = v;
    }
    if (__any((pm[0] > m[0] + 8.f) | (pm[1] > m[1] + 8.f))) {
#pragma unroll
      for (int qb = 0; qb < 2; ++qb) {
        const float mn = fmaxf(m[qb], pm[qb]);
        const float al = __expf(m[qb] - mn);
        m[qb] = mn;
        lsum[qb] *= al;
        float alT[4];
#pragma unroll
        for (int r = 0; r < 4; ++r)
          alT[r] = __shfl(al, (lane & 48) | (kg * 4 + r));
#pragma unroll
        for (int n = 0; n < 8; ++n)
#pragma unroll
          for (int r = 0; r < 4; ++r) o[qb][n][r] *= alT[r];
      }
    }
#pragma unroll
    for (int qb = 0; qb < 2; ++qb) {
      float rs = 0.f;
#pragma unroll
      for (int n = 0; n < 4; ++n)
#pragma unroll
        for (int r = 0; r < 4; ++r) {
          const float p = __expf(sc[qb][n][r] - m[qb]);
          sc[qb][n][r] = p;
          rs += p;
        }
      rs += __shfl_xor(rs, 16);
      rs += __shfl_xor(rs, 32);
      lsum[qb] += rs;
    }
    // pack P -> A-fragments (pure in-lane thanks to kappa-permuted V)
    bf16x8 pf[2][2];
#pragma unroll
    for (int qb = 0; qb < 2; ++qb)
#pragma unroll
      for (int ks = 0; ks < 2; ++ks)
#pragma unroll
        for (int r = 0; r < 4; ++r) {
          pf[qb][ks][r] = (short)f2b(sc[qb][2 * ks][r]);
          pf[qb][ks][r + 4] = (short)f2b(sc[qb][2 * ks + 1][r]);
        }
    // PV: o[qb][n] += pf[qb][ks] x vf(n,ks)
#pragma unroll
    for (int n = 0; n < 8; ++n)
#pragma unroll
      for (int ks = 0; ks < 2; ++ks) {
        const int voff = (n * 16 + l15) * 64 + ((ks * 32 + kg * 8) ^ xorv);
        bf16x8 vf = *reinterpret_cast<const bf16x8*>(&Vs[voff]);
#pragma unroll
        for (int qb = 0; qb < 2; ++qb)
          o[qb][n] = __builtin_amdgcn_mfma_f32_16x16x32_bf16(pf[qb][ks], vf,
                                                             o[qb][n], 0, 0, 0);
      }
  }

  // epilogue: o[qb][n][r] is O[q = qb*16+kg*4+r][d = n*16+l15]
  if (!splitq) {
    float invT[2][4];
#pragma unroll
    for (int qb = 0; qb < 2; ++qb) {
      const float inv = 1.0f / lsum[qb];
#pragma unroll
      for (int r = 0; r < 4; ++r)
        invT[qb][r] = __shfl(inv, (lane & 48) | (kg * 4 + r));
    }
#pragma unroll
    for (int qb = 0; qb < 2; ++qb) {
      const int t0 = qbase + w * 32 + qb * 16 + kg * 4;
#pragma unroll
      for (int n = 0; n < 8; ++n)
#pragma unroll
        for (int r = 0; r < 4; ++r)
          aout[(size_t)(b * T_ + t0 + r) * (H_ * D_) + h * D_ + n * 16 + l15] =
              f2b(o[qb][n][r] * invT[qb][r]);
    }
  } else {
    const int slot = bh * 8 + (qt - 8);
    if (kg == 0) {
#pragma unroll
      for (int qb = 0; qb < 2; ++qb) {
        float2 v;
        v.x = m[qb];
        v.y = lsum[qb];
        ml[(size_t)(slot * 2 + s) * 128 + w * 32 + qb * 16 + l15] = v;
      }
    }
    if (s == 1) {  // unnormalized partial into this q-tile's aout slot
#pragma unroll
      for (int qb = 0; qb < 2; ++qb) {
        const int t0 = qbase + w * 32 + qb * 16 + kg * 4;
#pragma unroll
        for (int n = 0; n < 8; ++n)
#pragma unroll
          for (int r = 0; r < 4; ++r)
            aout[(size_t)(b * T_ + t0 + r) * (H_ * D_) + h * D_ + n * 16 + l15] =
                f2b(o[qb][n][r]);
      }
    } else {       // unnormalized partial into scratch
#pragma unroll
      for (int qb = 0; qb < 2; ++qb) {
        const int row0 = w * 32 + qb * 16 + kg * 4;
#pragma unroll
        for (int n = 0; n < 8; ++n)
#pragma unroll
          for (int r = 0; r < 4; ++r)
            po0[((size_t)slot * 128 + row0 + r) * 128 + n * 16 + l15] =
                f2b(o[qb][n][r]);
      }
    }
  }
}

// ---------------- combine split-K partials (128-row q-tiles) ----------------
__global__ __launch_bounds__(256) void combine_kernel(u16* __restrict__ aout,
                                                      const u16* __restrict__ po0,
                                                      const float2* __restrict__ ml) {
  const int bh = blockIdx.x;        // 0..23
  const int qt8 = blockIdx.y;       // 0..7 -> qt = 8+qt8
  const int slot = bh * 8 + qt8;
  const int b = bh / H_, h = bh - b * H_;
  const int t0 = (qt8 + 8) * 128;
  const int tid = threadIdx.x;
  const int row = tid >> 1;
  const int colc = (tid & 1) << 6;  // 64-elem column chunk

  const float2 ml0 = ml[(size_t)(slot * 2 + 0) * 128 + row];
  const float2 ml1 = ml[(size_t)(slot * 2 + 1) * 128 + row];
  const float mm = fmaxf(ml0.x, ml1.x);
  const float c0 = __expf(ml0.x - mm), c1 = __expf(ml1.x - mm);
  const float inv = 1.0f / (ml0.y * c0 + ml1.y * c1);
  const float s0 = c0 * inv, s1 = c1 * inv;

  const u16* p0 = po0 + ((size_t)slot * 128 + row) * 128 + colc;
  u16* a = aout + (size_t)(b * T_ + t0 + row) * (H_ * D_) + h * D_ + colc;
#pragma unroll
  for (int j = 0; j < 8; ++j) {
    u16x8 v0 = *reinterpret_cast<const u16x8*>(p0 + j * 8);
    u16x8 v1 = *reinterpret_cast<const u16x8*>(a + j * 8);
    u16x8 outv;
#pragma unroll
    for (int e = 0; e < 8; ++e) outv[e] = f2b(b2f(v0[e]) * s0 + b2f(v1[e]) * s1);
    *reinterpret_cast<u16x8*>(a + j * 8) = outv;
  }
}

extern "C" void kernel_launch(void* const* d_in, const int* in_sizes, int n_in,
                              void* d_out, int out_size, void* d_ws, size_t ws_size,
                              hipStream_t stream) {
  const float* hidden = (const float*)d_in[0];
  const float* cosb   = (const float*)d_in[1];
  const float* sinb   = (const float*)d_in[2];
  // d_in[3] = attention_mask (pure causal; implemented analytically)
  const float* q_w  = (const float*)d_in[4];
  const float* k_w  = (const float*)d_in[5];
  const float* v_w  = (const float*)d_in[6];
  const float* o_w  = (const float*)d_in[7];
  const float* q_nw = (const float*)d_in[8];
  const float* k_nw = (const float*)d_in[9];
  float* out = (float*)d_out;

  // d_out (24MB) phase reuse: qkv_proj bf16 [0,16) -> po0 partials [0,6) -> final f32
  // (fully rewritten by o-gemm). ws: hidden_b/qkvw die before q_b/aout overwrite.
  char* ws = (char*)d_ws;
  const size_t MB = 1u << 20;
  u16*    hidden_b = (u16*)(ws);                        // [0,12)  phase 1
  u16*    qkvw     = (u16*)(ws + 12 * MB);              // [12,18) phase 1
  u16*    q_b      = (u16*)(ws);                        // [0,12)  phase 2+
  u16*    aout     = (u16*)(ws + 12 * MB);              // [12,24) phase 2+
  float2* ml       = (float2*)(ws + 24 * MB);           // [24,24.4)
  u16*    k_b      = (u16*)(ws + 24 * MB + 512 * 1024); // [24.5,26.5)
  u16*    vt_b     = (u16*)(ws + 26 * MB + 512 * 1024); // [26.5,28.5)
  u16*    owb      = (u16*)(ws + 28 * MB + 512 * 1024); // [28.5,33)
  u16*    qkv_proj = (u16*)d_out;                       // bf16 [4096][2048]
  u16*    po0      = (u16*)d_out;                       // attn phase: 6MB partials

  const dim3 blk(256);
  const int M = B_ * T_;  // 4096

  // fp32 -> bf16 converts (weights fused: qkvw rows = [q_w; k_w; v_w])
  {
    const int nh = (B_ * T_ * HID_) / 4;
    const int nq = (H_ * D_ * HID_) / 4;
    const int nk = (HKV_ * D_ * HID_) / 4;
    cvt_f32_bf16<<<2048, blk, 0, stream>>>(hidden, hidden_b, nh);
    cvt_f32_bf16<<<2048, blk, 0, stream>>>(q_w, qkvw, nq);
    cvt_f32_bf16<<<384, blk, 0, stream>>>(k_w, qkvw + (size_t)1536 * HID_, nk);
    cvt_f32_bf16<<<384, blk, 0, stream>>>(v_w, qkvw + (size_t)1792 * HID_, nk);
    cvt_f32_bf16<<<2048, blk, 0, stream>>>(o_w, owb, nq);
  }

  // fused QKV projection: [4096][2048] bf16
  gemm_bt<u16><<<dim3(NQKV_ / 128, M / 128), blk, 0, stream>>>(hidden_b, qkvw, qkv_proj,
                                                               M, NQKV_, HID_);

  norm_rope_cvt<<<16384, blk, 0, stream>>>(qkv_proj, cosb, sinb, q_nw, k_nw,
                                           q_b, k_b, vt_b);

  attn_kernel<<<dim3(B_ * H_, 24), blk, 0, stream>>>(q_b, k_b, vt_b, aout, po0, ml);
  combine_kernel<<<dim3(B_ * H_, 8), blk, 0, stream>>>(aout, po0, ml);

  gemm_bt<float><<<dim3(HID_ / 128, M / 128), blk, 0, stream>>>(aout, owb, out,
                                                                M, HID_, HID_);
}